// Round 7
// baseline (8280.672 us; speedup 1.0000x reference)
//
#include <hip/hip_runtime.h>
#include <cstdint>
#include <cstddef>

#define B_   64
#define T_   2048
#define C_   64
#define H_   256
#define G3_  768    // 3*H
#define HOR_ 96

typedef _Float16 h2 __attribute__((ext_vector_type(2)));
typedef _Float16 h4v __attribute__((ext_vector_type(4)));
typedef _Float16 h8 __attribute__((ext_vector_type(8)));
typedef _Float16 f16x8 __attribute__((ext_vector_type(8)));
typedef float f32x4 __attribute__((ext_vector_type(4)));
typedef int i32x4 __attribute__((ext_vector_type(4)));

// ---------------------------------------------------------------------------
// K1: cur[b,t,h] = sum_c x[b,t,c]*snn_w[h,c] + snn_b[h]   (fp32)
// Block (0,0) also zeroes the producer->consumer flags.
// ---------------------------------------------------------------------------
#define K1_TT 128
__global__ __launch_bounds__(256) void k_cur(const float* __restrict__ x,
                                             const float* __restrict__ w,
                                             const float* __restrict__ bias,
                                             float* __restrict__ cur,
                                             int* __restrict__ flags) {
  __shared__ float xs[K1_TT * C_];  // 32 KB
  const int b = blockIdx.x;
  const int t0 = blockIdx.y * K1_TT;
  const int tid = threadIdx.x;

  if (b == 0 && blockIdx.y == 0) {
#pragma unroll
    for (int i = 0; i < 4; i++) flags[tid + i * 256] = 0;
  }

  const float4* xsrc = (const float4*)(x + ((size_t)b * T_ + t0) * C_);
  float4* xdst = (float4*)xs;
#pragma unroll
  for (int i = 0; i < (K1_TT * C_ / 4) / 256; i++)
    xdst[tid + i * 256] = xsrc[tid + i * 256];

  float wr[C_];
  const float4* wp = (const float4*)(w + (size_t)tid * C_);
#pragma unroll
  for (int q = 0; q < C_ / 4; q++) {
    float4 v = wp[q];
    wr[4 * q + 0] = v.x; wr[4 * q + 1] = v.y;
    wr[4 * q + 2] = v.z; wr[4 * q + 3] = v.w;
  }
  const float bb = bias[tid];
  __syncthreads();

  for (int t = 0; t < K1_TT; t++) {
    const float4* xrow = (const float4*)(xs + t * C_);
    float a0 = 0.f, a1 = 0.f;
#pragma unroll
    for (int q = 0; q < C_ / 4; q += 2) {
      float4 v0 = xrow[q];
      float4 v1 = xrow[q + 1];
      a0 += wr[4 * q + 0] * v0.x + wr[4 * q + 1] * v0.y +
            wr[4 * q + 2] * v0.z + wr[4 * q + 3] * v0.w;
      a1 += wr[4 * q + 4] * v1.x + wr[4 * q + 5] * v1.y +
            wr[4 * q + 6] * v1.z + wr[4 * q + 7] * v1.w;
    }
    cur[((size_t)b * T_ + t0 + t) * H_ + tid] = a0 + a1 + bb;
  }
}

// ---------------------------------------------------------------------------
// K2: LIF scan per (b,h). Spikes stored as u8 (exact).
// ---------------------------------------------------------------------------
__global__ __launch_bounds__(64) void k_lif(const float* __restrict__ cur,
                                            unsigned char* __restrict__ spk) {
  const int b = blockIdx.x >> 2;
  const int h = ((blockIdx.x & 3) << 6) + threadIdx.x;
  const float* cp = cur + (size_t)b * T_ * H_ + h;
  unsigned char* sp = spk + (size_t)b * T_ * H_ + h;
  float mem = 0.f;
#pragma unroll 32
  for (int t = 0; t < T_; t++) {
    float c = cp[(size_t)t * H_];
    float reset = (mem > 1.0f) ? 1.0f : 0.0f;  // from previous mem
    mem = 0.9f * mem + c - reset;              // THR = 1
    sp[(size_t)t * H_] = (mem > 1.0f) ? (unsigned char)1 : (unsigned char)0;
  }
}

// ---------------------------------------------------------------------------
// K3+K4 FUSED — 256 threads/block, __launch_bounds__(256,1).
// ROUND-7: round-6's MFMA consumer was NUMERICALLY CORRECT (absmax canary
// held) but spilled at the 512-thr/128-VGPR budget (6.5ms, scratch reloads
// of W every step). Re-hosted at 256 thr where 256 arch VGPRs are PROVEN
// (rounds 1/4/5): W = 192 dwords/thread as i8 MFMA A-fragments; acc (48) and
// overflow park in AGPRs (gfx950 unified file, MFMA reads A/C from AGPR;
// launch_bounds(256,1) -> 1 wave/SIMD -> 512-reg unified budget). Biases
// moved to LDS (saves 48 arch regs). 8 consumer blocks x 8 batches; lanes
// 8..15 duplicate batches 0..7 (identical inputs -> identical values, no
// divergence) so the B/D tile stays 16 wide. Per step/wave: 48
// mfma_i32_16x16x64_i8 (matrix pipe) + ~90 VALU tail vs round-1's ~230 VALU
// — the scan leaves the saturated VALU pipe.
//  blocks 0..7    : GRU consumers, 8 batches each.
//  blocks 8..199  : gx producers — 3 per batch (round-1 tile, verbatim).
// ROUND-6 LESSON: weights must fit the GRANTED register budget (spill = 4x).
// ROUND-2 LESSON: no redundant per-SIMD issue (duplicate lanes here add
// MFMA-width, not VALU issue: tail computes 16 pairs either way).
// ---------------------------------------------------------------------------
#define GM 128
#define GN 128
#define AKP 40   // padded K-chunk stride (halves)
#define CTP 136  // C-transpose row stride (halves)
#define HQP 288  // h_q8 row pad (bytes)
#define DQ_ (0.0625f / (127.0f * 127.0f))
__global__ __launch_bounds__(256, 1) void k_fused(
    const float* __restrict__ x, const unsigned char* __restrict__ spk,
    const float* __restrict__ wih, const float* __restrict__ bih,
    _Float16* __restrict__ gx, const float* __restrict__ whh,
    const float* __restrict__ bhh, const float* __restrict__ head_w,
    const float* __restrict__ head_b, float* __restrict__ out,
    int* __restrict__ flags) {
  alignas(16) __shared__ _Float16 Ah[GM * AKP];   // 10 KB (producer)
  alignas(16) __shared__ _Float16 Bh[GN * AKP];   // 10 KB (producer)
  alignas(16) __shared__ _Float16 Ct[GM * CTP];   // 34 KB (producer)
  alignas(16) __shared__ unsigned char hlds[2][16][HQP];  // 9 KB (consumer)
  alignas(16) __shared__ float hb32[8][H_];       // 8 KB (consumer)
  alignas(16) __shared__ float blds[G3_];         // 3 KB (consumer biases)

  const int tid = threadIdx.x;
  const int lane = tid & 63;

  if (blockIdx.x >= 8) {
    // ===================== PRODUCER (round-1 tile, 256 thr) =====================
    const int pidx = blockIdx.x - 8;
    const int bb = pidx / 3;
    const int pp = pidx - bb * 3;
    const int wave = tid >> 6;        // 0..3
    const int ln = lane & 15;
    const int qd = lane >> 4;
    const int wm = (wave & 1) * 64;
    const int wn = ((wave >> 1) & 1) * 64;

    for (int mt = 0; mt < 16; mt++) {
      const int m0 = bb * 2048 + mt * 128;
      for (int nh = 0; nh < 2; nh++) {
        const int n0 = pp * 256 + nh * 128;
        f32x4 acc[4][4] = {};
        for (int kc = 0; kc < 10; kc++) {
          const int k0 = kc * 32;
          if (k0 < 64) {
#pragma unroll
            for (int i = 0; i < 4; i++) {
              int idx = tid + i * 256;
              int r = idx >> 3;
              int c4 = (idx & 7) * 4;
              float4 v = *(const float4*)(x + (size_t)(m0 + r) * C_ + k0 + c4);
              h2 lo, hi;
              lo.x = (_Float16)v.x; lo.y = (_Float16)v.y;
              hi.x = (_Float16)v.z; hi.y = (_Float16)v.w;
              h2* d = (h2*)&Ah[r * AKP + c4];
              d[0] = lo; d[1] = hi;
            }
          } else {
#pragma unroll
            for (int i = 0; i < 4; i++) {
              int idx = tid + i * 256;
              int r = idx >> 3;
              int c4 = (idx & 7) * 4;
              uchar4 u = *(const uchar4*)(spk + (size_t)(m0 + r) * H_ + (k0 - 64) + c4);
              h2 lo, hi;
              lo.x = (_Float16)(int)u.x; lo.y = (_Float16)(int)u.y;
              hi.x = (_Float16)(int)u.z; hi.y = (_Float16)(int)u.w;
              h2* d = (h2*)&Ah[r * AKP + c4];
              d[0] = lo; d[1] = hi;
            }
          }
#pragma unroll
          for (int i = 0; i < 4; i++) {
            int idx = tid + i * 256;
            int r = idx >> 3;
            int c4 = (idx & 7) * 4;
            float4 v = *(const float4*)(wih + (size_t)(n0 + r) * 320 + k0 + c4);
            h2 lo, hi;
            lo.x = (_Float16)v.x; lo.y = (_Float16)v.y;
            hi.x = (_Float16)v.z; hi.y = (_Float16)v.w;
            h2* d = (h2*)&Bh[r * AKP + c4];
            d[0] = lo; d[1] = hi;
          }
          __syncthreads();
          {
            f16x8 a[4], bbf[4];
#pragma unroll
            for (int mtl = 0; mtl < 4; mtl++)
              a[mtl] = *(const f16x8*)&Ah[(wm + mtl * 16 + ln) * AKP + qd * 8];
#pragma unroll
            for (int nt = 0; nt < 4; nt++)
              bbf[nt] = *(const f16x8*)&Bh[(wn + nt * 16 + ln) * AKP + qd * 8];
#pragma unroll
            for (int mtl = 0; mtl < 4; mtl++)
#pragma unroll
              for (int nt = 0; nt < 4; nt++)
                acc[mtl][nt] = __builtin_amdgcn_mfma_f32_16x16x32_f16(
                    a[mtl], bbf[nt], acc[mtl][nt], 0, 0, 0);
          }
          __syncthreads();
        }
        {
          float bias[4];
#pragma unroll
          for (int nt = 0; nt < 4; nt++) bias[nt] = bih[n0 + wn + nt * 16 + ln];
#pragma unroll
          for (int mtl = 0; mtl < 4; mtl++)
#pragma unroll
            for (int nt = 0; nt < 4; nt++) {
              int n = wn + nt * 16 + ln;
#pragma unroll
              for (int r = 0; r < 4; r++) {
                int m = wm + mtl * 16 + qd * 4 + r;
                Ct[m * CTP + n] = (_Float16)(acc[mtl][nt][r] + bias[nt]);
              }
            }
        }
        __syncthreads();
#pragma unroll
        for (int i = 0; i < 8; i++) {
          int idx = tid + i * 256;
          int r = idx >> 4;
          int c = (idx & 15) * 8;
          *(h8*)(gx + (size_t)(m0 + r) * G3_ + n0 + c) = *(const h8*)&Ct[r * CTP + c];
        }
        __syncthreads();  // stores drained before flag / Ct reuse
      }
      if (tid == 0)
        __hip_atomic_fetch_add(&flags[bb * 16 + mt], 1, __ATOMIC_RELEASE,
                               __HIP_MEMORY_SCOPE_AGENT);
    }
    return;
  }

  // ========== CONSUMER: 8 batches, MFMA i8 hh-matvec, fp32 tail ==========
  const int b0 = blockIdx.x << 3;   // batches b0..b0+7
  const int w = tid >> 6;           // wave 0..3: owns j16 tiles {4w..4w+3}
  const int lb = lane & 15;         // A-row / B-col; batch = b0 + (lb&7)
  const int lk = lane >> 4;         // k-group / D-row-group

  // ---- W fragments: wf[gate][jl][chunk], row = g*256 + (w*4+jl)*16 + lb ----
  i32x4 wf[3][4][4];   // 192 dwords (MFMA A operands -> AGPR-eligible)
  {
    const float qs = 2032.0f;  // 127 / 0.0625
#pragma unroll
    for (int g = 0; g < 3; g++)
#pragma unroll
      for (int jl = 0; jl < 4; jl++) {
        const float* row = whh + (size_t)(g * 256 + (w * 4 + jl) * 16 + lb) * H_;
#pragma unroll
        for (int c = 0; c < 4; c++) {
          const int kb = c * 64 + lk * 16;
          i32x4 v;
#pragma unroll
          for (int d = 0; d < 4; d++) {
            float4 f = *(const float4*)(row + kb + d * 4);
            v[d] = ((int)rintf(f.x * qs) & 255) | (((int)rintf(f.y * qs) & 255) << 8) |
                   (((int)rintf(f.z * qs) & 255) << 16) | (((int)rintf(f.w * qs) & 255) << 24);
          }
          wf[g][jl][c] = v;
        }
      }
  }

  // biases to LDS (f32), h-queue zeroed
  for (int i = tid; i < G3_; i += 256) blds[i] = bhh[i];
  for (int i = tid; i < (int)(2 * 16 * HQP / 4); i += 256) ((int*)hlds)[i] = 0;
  float ho[16];
#pragma unroll
  for (int i = 0; i < 16; i++) ho[i] = 0.f;
  __syncthreads();

  // per-lane gx base: batch b0+(lb&7), this wave's j-offset, k-group lk
  const _Float16* gxT = gx + (size_t)(b0 + (lb & 7)) * T_ * G3_ + w * 64 + lk * 4;
  int p = 0;
  for (int mt = 0; mt < 16; mt++) {
    if (tid < 8) {
      while (__hip_atomic_load(&flags[(b0 + tid) * 16 + mt], __ATOMIC_ACQUIRE,
                               __HIP_MEMORY_SCOPE_AGENT) < 3)
        __builtin_amdgcn_s_sleep(8);
    }
    __syncthreads();

    for (int tt = 0; tt < 128; tt++) {
      // gx for this step's 16 (j,b) pairs: 12 x b64, issued first (MFMA covers)
      const _Float16* gp = gxT + (size_t)(mt * 128 + tt) * G3_;
      h4v gv[3][4];
#pragma unroll
      for (int g = 0; g < 3; g++)
#pragma unroll
        for (int jl = 0; jl < 4; jl++)
          gv[g][jl] = *(const h4v*)(gp + g * 256 + jl * 16);

      // h B-fragments: row b (= lb), k-contiguous
      i32x4 hf[4];
#pragma unroll
      for (int c = 0; c < 4; c++)
        hf[c] = *(const i32x4*)&hlds[p][lb][c * 64 + lk * 16];

      // 48 MFMA: D[j,b] = sum_k W[j,k] h[k,b]; i32 exact == sdot4 path
      i32x4 acc[3][4];
#pragma unroll
      for (int g = 0; g < 3; g++)
#pragma unroll
        for (int jl = 0; jl < 4; jl++) {
          i32x4 a = {0, 0, 0, 0};
#pragma unroll
          for (int c = 0; c < 4; c++)
            a = __builtin_amdgcn_mfma_i32_16x16x64_i8(wf[g][jl][c], hf[c], a, 0, 0, 0);
          acc[g][jl] = a;
        }

      // tail: 16 (j, b=lb&7) pairs; gates in-lane (same (row,col) across tiles)
#pragma unroll
      for (int jl = 0; jl < 4; jl++) {
        const int jb = (w * 4 + jl) * 16 + lk * 4;
        const float4 bR4 = *(const float4*)&blds[jb];
        const float4 bZ4 = *(const float4*)&blds[H_ + jb];
        const float4 bN4 = *(const float4*)&blds[2 * H_ + jb];
        int packed = 0;
#pragma unroll
        for (int r = 0; r < 4; r++) {
          const float xr = (float)gv[0][jl][r];
          const float xz = (float)gv[1][jl][r];
          const float xn = (float)gv[2][jl][r];
          const float bRr = (r == 0) ? bR4.x : (r == 1) ? bR4.y : (r == 2) ? bR4.z : bR4.w;
          const float bZr = (r == 0) ? bZ4.x : (r == 1) ? bZ4.y : (r == 2) ? bZ4.z : bZ4.w;
          const float bNr = (r == 0) ? bN4.x : (r == 1) ? bN4.y : (r == 2) ? bN4.z : bN4.w;
          const float ar = (float)acc[0][jl][r] * DQ_ + bRr;
          const float az = (float)acc[1][jl][r] * DQ_ + bZr;
          const float an = (float)acc[2][jl][r] * DQ_ + bNr;
          const float rr = 1.f / (1.f + __expf(-(xr + ar)));
          const float zz = 1.f / (1.f + __expf(-(xz + az)));
          const float pre = xn + rr * an;
          const float e = __expf(2.f * pre);   // tanh = 1 - 2/(e^{2x}+1)
          const float nn = 1.f - 2.f / (e + 1.f);
          const float h = (1.f - zz) * nn + zz * ho[jl * 4 + r];
          ho[jl * 4 + r] = h;
          packed |= ((int)rintf(h * 127.0f) & 255) << (8 * r);
        }
        *(int*)&hlds[p ^ 1][lb][jb] = packed;
      }
      p ^= 1;
      __syncthreads();   // the ONLY barrier per step
    }
  }

  // ---- head: h [8 x 256] -> out [8 x 96] ----
  if (lb < 8) {
#pragma unroll
    for (int jl = 0; jl < 4; jl++)
#pragma unroll
      for (int r = 0; r < 4; r++)
        hb32[lb][(w * 4 + jl) * 16 + lk * 4 + r] = ho[jl * 4 + r];
  }
  __syncthreads();

#pragma unroll
  for (int i = 0; i < 3; i++) {
    const int o = tid + i * 256;          // 0..767
    const int bb2 = o / 96, rr2 = o % 96;
    const float4* hw = (const float4*)(head_w + (size_t)rr2 * H_);
    const float4* hv = (const float4*)&hb32[bb2][0];
    float acc2 = head_b[rr2];
#pragma unroll
    for (int q = 0; q < H_ / 4; q++) {
      float4 w4 = hw[q];
      float4 v4 = hv[q];
      acc2 += w4.x * v4.x + w4.y * v4.y + w4.z * v4.z + w4.w * v4.w;
    }
    out[(size_t)(b0 + bb2) * HOR_ + rr2] = acc2;
  }
}

// ---------------------------------------------------------------------------
extern "C" void kernel_launch(void* const* d_in, const int* in_sizes, int n_in,
                              void* d_out, int out_size, void* d_ws, size_t ws_size,
                              hipStream_t stream) {
  const float* x      = (const float*)d_in[0];
  const float* snn_w  = (const float*)d_in[1];
  const float* snn_b  = (const float*)d_in[2];
  const float* wih    = (const float*)d_in[3];
  const float* whh    = (const float*)d_in[4];
  const float* bih    = (const float*)d_in[5];
  const float* bhh    = (const float*)d_in[6];
  const float* head_w = (const float*)d_in[7];
  const float* head_b = (const float*)d_in[8];
  float* out = (float*)d_out;

  // ws layout (235 MB + 4 KB flags):
  //   [0, 201326592)          gx fp16 [131072,768]
  //   [0, 134217728)          cur fp32 [131072,256] — alias, dead before fused
  //   [201326592, 234881024)  spk u8 [131072,256]
  //   [234881024, 234885120)  flags int[1024]
  char* ws = (char*)d_ws;
  _Float16* gx = (_Float16*)ws;
  float* cur = (float*)ws;
  unsigned char* spk = (unsigned char*)(ws + (size_t)201326592);
  int* flags = (int*)(ws + (size_t)234881024);

  k_cur<<<dim3(B_, T_ / K1_TT), 256, 0, stream>>>(x, snn_w, snn_b, cur, flags);
  k_lif<<<dim3(256), 64, 0, stream>>>(cur, spk);
  k_fused<<<dim3(200), 256, 0, stream>>>(x, spk, wih, bih, gx, whh, bhh,
                                         head_w, head_b, out, flags);
}

// Round 8
// 7273.878 us; speedup vs baseline: 1.1384x; 1.1384x over previous
//
#include <hip/hip_runtime.h>
#include <cstdint>
#include <cstddef>

#define B_   64
#define T_   2048
#define C_   64
#define H_   256
#define G3_  768    // 3*H
#define HOR_ 96

typedef _Float16 h2 __attribute__((ext_vector_type(2)));
typedef _Float16 h4v __attribute__((ext_vector_type(4)));
typedef _Float16 h8 __attribute__((ext_vector_type(8)));
typedef _Float16 f16x8 __attribute__((ext_vector_type(8)));
typedef float f32x4 __attribute__((ext_vector_type(4)));
typedef int i32x4 __attribute__((ext_vector_type(4)));

// ---------------------------------------------------------------------------
// K1: cur[b,t,h] = sum_c x[b,t,c]*snn_w[h,c] + snn_b[h]   (fp32)
// Block (0,0) also zeroes the producer->consumer flags.
// ---------------------------------------------------------------------------
#define K1_TT 128
__global__ __launch_bounds__(256) void k_cur(const float* __restrict__ x,
                                             const float* __restrict__ w,
                                             const float* __restrict__ bias,
                                             float* __restrict__ cur,
                                             int* __restrict__ flags) {
  __shared__ float xs[K1_TT * C_];  // 32 KB
  const int b = blockIdx.x;
  const int t0 = blockIdx.y * K1_TT;
  const int tid = threadIdx.x;

  if (b == 0 && blockIdx.y == 0) {
#pragma unroll
    for (int i = 0; i < 4; i++) flags[tid + i * 256] = 0;
  }

  const float4* xsrc = (const float4*)(x + ((size_t)b * T_ + t0) * C_);
  float4* xdst = (float4*)xs;
#pragma unroll
  for (int i = 0; i < (K1_TT * C_ / 4) / 256; i++)
    xdst[tid + i * 256] = xsrc[tid + i * 256];

  float wr[C_];
  const float4* wp = (const float4*)(w + (size_t)tid * C_);
#pragma unroll
  for (int q = 0; q < C_ / 4; q++) {
    float4 v = wp[q];
    wr[4 * q + 0] = v.x; wr[4 * q + 1] = v.y;
    wr[4 * q + 2] = v.z; wr[4 * q + 3] = v.w;
  }
  const float bb = bias[tid];
  __syncthreads();

  for (int t = 0; t < K1_TT; t++) {
    const float4* xrow = (const float4*)(xs + t * C_);
    float a0 = 0.f, a1 = 0.f;
#pragma unroll
    for (int q = 0; q < C_ / 4; q += 2) {
      float4 v0 = xrow[q];
      float4 v1 = xrow[q + 1];
      a0 += wr[4 * q + 0] * v0.x + wr[4 * q + 1] * v0.y +
            wr[4 * q + 2] * v0.z + wr[4 * q + 3] * v0.w;
      a1 += wr[4 * q + 4] * v1.x + wr[4 * q + 5] * v1.y +
            wr[4 * q + 6] * v1.z + wr[4 * q + 7] * v1.w;
    }
    cur[((size_t)b * T_ + t0 + t) * H_ + tid] = a0 + a1 + bb;
  }
}

// ---------------------------------------------------------------------------
// K2: LIF scan per (b,h). Spikes stored as u8 (exact).
// ---------------------------------------------------------------------------
__global__ __launch_bounds__(64) void k_lif(const float* __restrict__ cur,
                                            unsigned char* __restrict__ spk) {
  const int b = blockIdx.x >> 2;
  const int h = ((blockIdx.x & 3) << 6) + threadIdx.x;
  const float* cp = cur + (size_t)b * T_ * H_ + h;
  unsigned char* sp = spk + (size_t)b * T_ * H_ + h;
  float mem = 0.f;
#pragma unroll 32
  for (int t = 0; t < T_; t++) {
    float c = cp[(size_t)t * H_];
    float reset = (mem > 1.0f) ? 1.0f : 0.0f;  // from previous mem
    mem = 0.9f * mem + c - reset;              // THR = 1
    sp[(size_t)t * H_] = (mem > 1.0f) ? (unsigned char)1 : (unsigned char)0;
  }
}

// ---------------------------------------------------------------------------
// K3+K4 FUSED — 256 threads/block, __launch_bounds__(256,1).
// ROUND-8: round-7 proved the MFMA consumer is numerically right but the
// compiler would NOT park W fragments in AGPRs from the builtin (kept them
// VGPR-class, spilled ~50 dwords, 8ms). Fix: MFMA via INLINE ASM with "a"
// constraints on the A operands — AGPR becomes the only legal home for wf
// (ISA §10: A from VGPR or AGPR on gfx950). AGPR=192 (wf), arch VGPR ~160
// (acc 48 + hf 16 + gv 24 + ho 16 + temps) < 256 proven budget. Hazards:
// same-dest MFMA chains need no nops; standalone s_nop 7 x2 after the MFMA
// loop covers MFMA-write -> VALU-read (asm is opaque to the hazard pass).
// 16 UNIQUE batches/block (no duplicated lanes — round-2 lesson): tail = 16
// h/thread for 16 batches vs round-1's 1 h for 1 batch.
//  blocks 0..3    : GRU consumers, 16 batches each.
//  blocks 4..195  : gx producers — 3 per batch (round-1 tile, verbatim).
// ROUND-7 LESSON: builtins never AGPR-home operands; force with asm "a".
// ROUND-6 LESSON: weights must fit the GRANTED budget (spill = 4-5x).
// ---------------------------------------------------------------------------
#define GM 128
#define GN 128
#define AKP 40   // padded K-chunk stride (halves)
#define CTP 136  // C-transpose row stride (halves)
#define HQP 288  // h_q8 row pad (bytes)
#define DQ_ (0.0625f / (127.0f * 127.0f))
__global__ __launch_bounds__(256, 1) void k_fused(
    const float* __restrict__ x, const unsigned char* __restrict__ spk,
    const float* __restrict__ wih, const float* __restrict__ bih,
    _Float16* __restrict__ gx, const float* __restrict__ whh,
    const float* __restrict__ bhh, const float* __restrict__ head_w,
    const float* __restrict__ head_b, float* __restrict__ out,
    int* __restrict__ flags) {
  alignas(16) __shared__ _Float16 Ah[GM * AKP];   // 10 KB (producer)
  alignas(16) __shared__ _Float16 Bh[GN * AKP];   // 10 KB (producer)
  alignas(16) __shared__ _Float16 Ct[GM * CTP];   // 34 KB (producer)
  alignas(16) __shared__ unsigned char hlds[2][16][HQP];  // 9 KB (consumer)
  alignas(16) __shared__ float hb32[16][H_];      // 16 KB (consumer)
  alignas(16) __shared__ float blds[G3_];         // 3 KB (consumer biases)

  const int tid = threadIdx.x;
  const int lane = tid & 63;

  if (blockIdx.x >= 4) {
    // ===================== PRODUCER (round-1 tile, 256 thr) =====================
    const int pidx = blockIdx.x - 4;
    const int bb = pidx / 3;
    const int pp = pidx - bb * 3;
    const int wave = tid >> 6;        // 0..3
    const int ln = lane & 15;
    const int qd = lane >> 4;
    const int wm = (wave & 1) * 64;
    const int wn = ((wave >> 1) & 1) * 64;

    for (int mt = 0; mt < 16; mt++) {
      const int m0 = bb * 2048 + mt * 128;
      for (int nh = 0; nh < 2; nh++) {
        const int n0 = pp * 256 + nh * 128;
        f32x4 acc[4][4] = {};
        for (int kc = 0; kc < 10; kc++) {
          const int k0 = kc * 32;
          if (k0 < 64) {
#pragma unroll
            for (int i = 0; i < 4; i++) {
              int idx = tid + i * 256;
              int r = idx >> 3;
              int c4 = (idx & 7) * 4;
              float4 v = *(const float4*)(x + (size_t)(m0 + r) * C_ + k0 + c4);
              h2 lo, hi;
              lo.x = (_Float16)v.x; lo.y = (_Float16)v.y;
              hi.x = (_Float16)v.z; hi.y = (_Float16)v.w;
              h2* d = (h2*)&Ah[r * AKP + c4];
              d[0] = lo; d[1] = hi;
            }
          } else {
#pragma unroll
            for (int i = 0; i < 4; i++) {
              int idx = tid + i * 256;
              int r = idx >> 3;
              int c4 = (idx & 7) * 4;
              uchar4 u = *(const uchar4*)(spk + (size_t)(m0 + r) * H_ + (k0 - 64) + c4);
              h2 lo, hi;
              lo.x = (_Float16)(int)u.x; lo.y = (_Float16)(int)u.y;
              hi.x = (_Float16)(int)u.z; hi.y = (_Float16)(int)u.w;
              h2* d = (h2*)&Ah[r * AKP + c4];
              d[0] = lo; d[1] = hi;
            }
          }
#pragma unroll
          for (int i = 0; i < 4; i++) {
            int idx = tid + i * 256;
            int r = idx >> 3;
            int c4 = (idx & 7) * 4;
            float4 v = *(const float4*)(wih + (size_t)(n0 + r) * 320 + k0 + c4);
            h2 lo, hi;
            lo.x = (_Float16)v.x; lo.y = (_Float16)v.y;
            hi.x = (_Float16)v.z; hi.y = (_Float16)v.w;
            h2* d = (h2*)&Bh[r * AKP + c4];
            d[0] = lo; d[1] = hi;
          }
          __syncthreads();
          {
            f16x8 a[4], bbf[4];
#pragma unroll
            for (int mtl = 0; mtl < 4; mtl++)
              a[mtl] = *(const f16x8*)&Ah[(wm + mtl * 16 + ln) * AKP + qd * 8];
#pragma unroll
            for (int nt = 0; nt < 4; nt++)
              bbf[nt] = *(const f16x8*)&Bh[(wn + nt * 16 + ln) * AKP + qd * 8];
#pragma unroll
            for (int mtl = 0; mtl < 4; mtl++)
#pragma unroll
              for (int nt = 0; nt < 4; nt++)
                acc[mtl][nt] = __builtin_amdgcn_mfma_f32_16x16x32_f16(
                    a[mtl], bbf[nt], acc[mtl][nt], 0, 0, 0);
          }
          __syncthreads();
        }
        {
          float bias[4];
#pragma unroll
          for (int nt = 0; nt < 4; nt++) bias[nt] = bih[n0 + wn + nt * 16 + ln];
#pragma unroll
          for (int mtl = 0; mtl < 4; mtl++)
#pragma unroll
            for (int nt = 0; nt < 4; nt++) {
              int n = wn + nt * 16 + ln;
#pragma unroll
              for (int r = 0; r < 4; r++) {
                int m = wm + mtl * 16 + qd * 4 + r;
                Ct[m * CTP + n] = (_Float16)(acc[mtl][nt][r] + bias[nt]);
              }
            }
        }
        __syncthreads();
#pragma unroll
        for (int i = 0; i < 8; i++) {
          int idx = tid + i * 256;
          int r = idx >> 4;
          int c = (idx & 15) * 8;
          *(h8*)(gx + (size_t)(m0 + r) * G3_ + n0 + c) = *(const h8*)&Ct[r * CTP + c];
        }
        __syncthreads();  // stores drained before flag / Ct reuse
      }
      if (tid == 0)
        __hip_atomic_fetch_add(&flags[bb * 16 + mt], 1, __ATOMIC_RELEASE,
                               __HIP_MEMORY_SCOPE_AGENT);
    }
    return;
  }

  // ========== CONSUMER: 16 batches, AGPR-W MFMA hh-matvec, fp32 tail ==========
  const int b0 = blockIdx.x << 4;   // batches b0..b0+15
  const int w = tid >> 6;           // wave 0..3: owns j-range [w*64, w*64+64)
  const int lb = lane & 15;         // A-row idx / B-col = batch b0+lb
  const int lk = lane >> 4;         // k-group / D-row-group

  // ---- W fragments: wf[gate][jl][chunk], row = g*256 + (w*4+jl)*16 + lb ----
  // Used ONLY as "a"-constrained asm inputs -> RA homes them in AGPRs.
  i32x4 wf[3][4][4];   // 192 dwords -> AGPR
  {
    const float qs = 2032.0f;  // 127 / 0.0625
#pragma unroll
    for (int g = 0; g < 3; g++)
#pragma unroll
      for (int jl = 0; jl < 4; jl++) {
        const float* row = whh + (size_t)(g * 256 + (w * 4 + jl) * 16 + lb) * H_;
#pragma unroll
        for (int c = 0; c < 4; c++) {
          const int kb = c * 64 + lk * 16;
          i32x4 v;
#pragma unroll
          for (int d = 0; d < 4; d++) {
            float4 f = *(const float4*)(row + kb + d * 4);
            v[d] = ((int)rintf(f.x * qs) & 255) | (((int)rintf(f.y * qs) & 255) << 8) |
                   (((int)rintf(f.z * qs) & 255) << 16) | (((int)rintf(f.w * qs) & 255) << 24);
          }
          wf[g][jl][c] = v;
        }
      }
  }

  // biases to LDS (f32), h-queue zeroed
  for (int i = tid; i < G3_; i += 256) blds[i] = bhh[i];
  for (int i = tid; i < (int)(2 * 16 * HQP / 4); i += 256) ((int*)hlds)[i] = 0;
  float ho[16];
#pragma unroll
  for (int i = 0; i < 16; i++) ho[i] = 0.f;
  __syncthreads();

  // per-lane gx base: batch b0+lb, this wave's j-offset, k-group lk
  const _Float16* gxT = gx + (size_t)(b0 + lb) * T_ * G3_ + w * 64 + lk * 4;
  int p = 0;
  for (int mt = 0; mt < 16; mt++) {
    if (tid < 16) {
      while (__hip_atomic_load(&flags[(b0 + tid) * 16 + mt], __ATOMIC_ACQUIRE,
                               __HIP_MEMORY_SCOPE_AGENT) < 3)
        __builtin_amdgcn_s_sleep(8);
    }
    __syncthreads();

    for (int tt = 0; tt < 128; tt++) {
      // gx for this step's 16 (j,b) pairs: 12 x b64, issued first
      const _Float16* gp = gxT + (size_t)(mt * 128 + tt) * G3_;
      h4v gv[3][4];
#pragma unroll
      for (int g = 0; g < 3; g++)
#pragma unroll
        for (int jl = 0; jl < 4; jl++)
          gv[g][jl] = *(const h4v*)(gp + g * 256 + jl * 16);

      // h B-fragments: row b (= lb), k-contiguous
      i32x4 hf[4];
#pragma unroll
      for (int c = 0; c < 4; c++)
        hf[c] = *(const i32x4*)&hlds[p][lb][c * 64 + lk * 16];

      // 48 MFMA via inline asm: A operands from AGPR ("a"), B from VGPR.
      // Same-dest chains need no nops; D->VALU hazard covered after loop.
      i32x4 acc[3][4];
#pragma unroll
      for (int g = 0; g < 3; g++)
#pragma unroll
        for (int jl = 0; jl < 4; jl++) {
          i32x4 a = {0, 0, 0, 0};
          asm volatile(
              "v_mfma_i32_16x16x64_i8 %0, %1, %5, %0\n\t"
              "v_mfma_i32_16x16x64_i8 %0, %2, %6, %0\n\t"
              "v_mfma_i32_16x16x64_i8 %0, %3, %7, %0\n\t"
              "v_mfma_i32_16x16x64_i8 %0, %4, %8, %0"
              : "+v"(a)
              : "a"(wf[g][jl][0]), "a"(wf[g][jl][1]),
                "a"(wf[g][jl][2]), "a"(wf[g][jl][3]),
                "v"(hf[0]), "v"(hf[1]), "v"(hf[2]), "v"(hf[3]));
          acc[g][jl] = a;
        }
      asm volatile("s_nop 7\n\ts_nop 7");  // MFMA-write -> VALU-read hazard

      // tail: 16 (j, b=lb) pairs; gates in-lane (same (row,col) across tiles)
#pragma unroll
      for (int jl = 0; jl < 4; jl++) {
        const int jb = (w * 4 + jl) * 16 + lk * 4;
        const float4 bR4 = *(const float4*)&blds[jb];
        const float4 bZ4 = *(const float4*)&blds[H_ + jb];
        const float4 bN4 = *(const float4*)&blds[2 * H_ + jb];
        int packed = 0;
#pragma unroll
        for (int r = 0; r < 4; r++) {
          const float xr = (float)gv[0][jl][r];
          const float xz = (float)gv[1][jl][r];
          const float xn = (float)gv[2][jl][r];
          const float bRr = (r == 0) ? bR4.x : (r == 1) ? bR4.y : (r == 2) ? bR4.z : bR4.w;
          const float bZr = (r == 0) ? bZ4.x : (r == 1) ? bZ4.y : (r == 2) ? bZ4.z : bZ4.w;
          const float bNr = (r == 0) ? bN4.x : (r == 1) ? bN4.y : (r == 2) ? bN4.z : bN4.w;
          const float ar = (float)acc[0][jl][r] * DQ_ + bRr;
          const float az = (float)acc[1][jl][r] * DQ_ + bZr;
          const float an = (float)acc[2][jl][r] * DQ_ + bNr;
          const float rr = 1.f / (1.f + __expf(-(xr + ar)));
          const float zz = 1.f / (1.f + __expf(-(xz + az)));
          const float pre = xn + rr * an;
          const float e = __expf(2.f * pre);   // tanh = 1 - 2/(e^{2x}+1)
          const float nn = 1.f - 2.f / (e + 1.f);
          const float h = (1.f - zz) * nn + zz * ho[jl * 4 + r];
          ho[jl * 4 + r] = h;
          packed |= ((int)rintf(h * 127.0f) & 255) << (8 * r);
        }
        *(int*)&hlds[p ^ 1][lb][jb] = packed;
      }
      p ^= 1;
      __syncthreads();   // the ONLY barrier per step
    }
  }

  // ---- head: h [16 x 256] -> out [16 x 96] ----
#pragma unroll
  for (int jl = 0; jl < 4; jl++)
#pragma unroll
    for (int r = 0; r < 4; r++)
      hb32[lb][w * 64 + jl * 16 + lk * 4 + r] = ho[jl * 4 + r];
  __syncthreads();

#pragma unroll
  for (int i = 0; i < 6; i++) {
    const int o = tid + i * 256;          // 0..1535
    const int bb2 = o / 96, rr2 = o % 96;
    const float4* hw = (const float4*)(head_w + (size_t)rr2 * H_);
    const float4* hv = (const float4*)&hb32[bb2][0];
    float acc2 = head_b[rr2];
#pragma unroll
    for (int q = 0; q < H_ / 4; q++) {
      float4 w4 = hw[q];
      float4 v4 = hv[q];
      acc2 += w4.x * v4.x + w4.y * v4.y + w4.z * v4.z + w4.w * v4.w;
    }
    out[(size_t)(b0 + bb2) * HOR_ + rr2] = acc2;
  }
}

// ---------------------------------------------------------------------------
extern "C" void kernel_launch(void* const* d_in, const int* in_sizes, int n_in,
                              void* d_out, int out_size, void* d_ws, size_t ws_size,
                              hipStream_t stream) {
  const float* x      = (const float*)d_in[0];
  const float* snn_w  = (const float*)d_in[1];
  const float* snn_b  = (const float*)d_in[2];
  const float* wih    = (const float*)d_in[3];
  const float* whh    = (const float*)d_in[4];
  const float* bih    = (const float*)d_in[5];
  const float* bhh    = (const float*)d_in[6];
  const float* head_w = (const float*)d_in[7];
  const float* head_b = (const float*)d_in[8];
  float* out = (float*)d_out;

  // ws layout (235 MB + 4 KB flags):
  //   [0, 201326592)          gx fp16 [131072,768]
  //   [0, 134217728)          cur fp32 [131072,256] — alias, dead before fused
  //   [201326592, 234881024)  spk u8 [131072,256]
  //   [234881024, 234885120)  flags int[1024]
  char* ws = (char*)d_ws;
  _Float16* gx = (_Float16*)ws;
  float* cur = (float*)ws;
  unsigned char* spk = (unsigned char*)(ws + (size_t)201326592);
  int* flags = (int*)(ws + (size_t)234881024);

  k_cur<<<dim3(B_, T_ / K1_TT), 256, 0, stream>>>(x, snn_w, snn_b, cur, flags);
  k_lif<<<dim3(256), 64, 0, stream>>>(cur, spk);
  k_fused<<<dim3(196), 256, 0, stream>>>(x, spk, wih, bih, gx, whh, bhh,
                                         head_w, head_b, out, flags);
}

// Round 10
// 6842.195 us; speedup vs baseline: 1.2102x; 1.0631x over previous
//
#include <hip/hip_runtime.h>
#include <cstdint>
#include <cstddef>

#define B_   64
#define T_   2048
#define C_   64
#define H_   256
#define G3_  768    // 3*H
#define HOR_ 96

typedef _Float16 h2 __attribute__((ext_vector_type(2)));
typedef _Float16 h4v __attribute__((ext_vector_type(4)));
typedef _Float16 h8 __attribute__((ext_vector_type(8)));
typedef _Float16 f16x8 __attribute__((ext_vector_type(8)));
typedef float f32x4 __attribute__((ext_vector_type(4)));
typedef int i32x4 __attribute__((ext_vector_type(4)));

// ---------------------------------------------------------------------------
// K1: cur[b,t,h] = sum_c x[b,t,c]*snn_w[h,c] + snn_b[h]   (fp32)
// Block (0,0) also zeroes the producer->consumer flags.
// ---------------------------------------------------------------------------
#define K1_TT 128
__global__ __launch_bounds__(256) void k_cur(const float* __restrict__ x,
                                             const float* __restrict__ w,
                                             const float* __restrict__ bias,
                                             float* __restrict__ cur,
                                             int* __restrict__ flags) {
  __shared__ float xs[K1_TT * C_];  // 32 KB
  const int b = blockIdx.x;
  const int t0 = blockIdx.y * K1_TT;
  const int tid = threadIdx.x;

  if (b == 0 && blockIdx.y == 0) {
#pragma unroll
    for (int i = 0; i < 4; i++) flags[tid + i * 256] = 0;
  }

  const float4* xsrc = (const float4*)(x + ((size_t)b * T_ + t0) * C_);
  float4* xdst = (float4*)xs;
#pragma unroll
  for (int i = 0; i < (K1_TT * C_ / 4) / 256; i++)
    xdst[tid + i * 256] = xsrc[tid + i * 256];

  float wr[C_];
  const float4* wp = (const float4*)(w + (size_t)tid * C_);
#pragma unroll
  for (int q = 0; q < C_ / 4; q++) {
    float4 v = wp[q];
    wr[4 * q + 0] = v.x; wr[4 * q + 1] = v.y;
    wr[4 * q + 2] = v.z; wr[4 * q + 3] = v.w;
  }
  const float bb = bias[tid];
  __syncthreads();

  for (int t = 0; t < K1_TT; t++) {
    const float4* xrow = (const float4*)(xs + t * C_);
    float a0 = 0.f, a1 = 0.f;
#pragma unroll
    for (int q = 0; q < C_ / 4; q += 2) {
      float4 v0 = xrow[q];
      float4 v1 = xrow[q + 1];
      a0 += wr[4 * q + 0] * v0.x + wr[4 * q + 1] * v0.y +
            wr[4 * q + 2] * v0.z + wr[4 * q + 3] * v0.w;
      a1 += wr[4 * q + 4] * v1.x + wr[4 * q + 5] * v1.y +
            wr[4 * q + 6] * v1.z + wr[4 * q + 7] * v1.w;
    }
    cur[((size_t)b * T_ + t0 + t) * H_ + tid] = a0 + a1 + bb;
  }
}

// ---------------------------------------------------------------------------
// K2: LIF scan per (b,h). Spikes stored as u8 (exact).
// ---------------------------------------------------------------------------
__global__ __launch_bounds__(64) void k_lif(const float* __restrict__ cur,
                                            unsigned char* __restrict__ spk) {
  const int b = blockIdx.x >> 2;
  const int h = ((blockIdx.x & 3) << 6) + threadIdx.x;
  const float* cp = cur + (size_t)b * T_ * H_ + h;
  unsigned char* sp = spk + (size_t)b * T_ * H_ + h;
  float mem = 0.f;
#pragma unroll 32
  for (int t = 0; t < T_; t++) {
    float c = cp[(size_t)t * H_];
    float reset = (mem > 1.0f) ? 1.0f : 0.0f;  // from previous mem
    mem = 0.9f * mem + c - reset;              // THR = 1
    sp[(size_t)t * H_] = (mem > 1.0f) ? (unsigned char)1 : (unsigned char)0;
  }
}

// ---------------------------------------------------------------------------
// K3+K4 FUSED — 256 threads/block, __launch_bounds__(256) (round-1 budget).
// ROUND-9 (re-run; round-9 bench was an infra failure, no data): 4th and
// FINAL MFMA attempt, constraints inverted. Established:
//  - numerics of the i8 MFMA consumer are correct (absmax canary, 3 rounds)
//  - W as PLAIN VGPR data (192 dwords) is spill-safe (round-1: VGPR=256,
//    no scratch, 1630us)
//  - the allocator refuses AGPR homing of asm INPUTS (round-8, 7ms)
// So: acc in AGPR via "+a" on the MFMA D/C operand (the natural pre-gfx908
// pattern), W stays plain VGPR. Arch pressure: wf 192 + hf 16 + gv 24 +
// ho 16 + temps ~= 250 ~= round-1's proven fit. Hazards (asm is opaque to
// the hazard pass): s_nop 1 before first MFMA (accvgpr_write zero-init ->
// MFMA C-read); s_nop 7 x2 after MFMA blocks (MFMA write -> accvgpr_read);
// acc extraction in C++ so compiler inserts its own reads w/ hazards.
//  blocks 0..3    : GRU consumers, 16 batches each.
//  blocks 4..195  : gx producers — 3 per batch (round-1 tile, verbatim).
// PRE-COMMITTED READ: >=3ms -> MFMA path dead on this toolchain, revert.
// ---------------------------------------------------------------------------
#define GM 128
#define GN 128
#define AKP 40   // padded K-chunk stride (halves)
#define CTP 136  // C-transpose row stride (halves)
#define HQP 288  // h_q8 row pad (bytes)
#define DQ_ (0.0625f / (127.0f * 127.0f))
__global__ __launch_bounds__(256) void k_fused(
    const float* __restrict__ x, const unsigned char* __restrict__ spk,
    const float* __restrict__ wih, const float* __restrict__ bih,
    _Float16* __restrict__ gx, const float* __restrict__ whh,
    const float* __restrict__ bhh, const float* __restrict__ head_w,
    const float* __restrict__ head_b, float* __restrict__ out,
    int* __restrict__ flags) {
  alignas(16) __shared__ _Float16 Ah[GM * AKP];   // 10 KB (producer)
  alignas(16) __shared__ _Float16 Bh[GN * AKP];   // 10 KB (producer)
  alignas(16) __shared__ _Float16 Ct[GM * CTP];   // 34 KB (producer)
  alignas(16) __shared__ unsigned char hlds[2][16][HQP];  // 9 KB (consumer)
  alignas(16) __shared__ float hb32[16][H_];      // 16 KB (consumer)
  alignas(16) __shared__ float blds[G3_];         // 3 KB (consumer biases)

  const int tid = threadIdx.x;
  const int lane = tid & 63;

  if (blockIdx.x >= 4) {
    // ===================== PRODUCER (round-1 tile, 256 thr) =====================
    const int pidx = blockIdx.x - 4;
    const int bb = pidx / 3;
    const int pp = pidx - bb * 3;
    const int wave = tid >> 6;        // 0..3
    const int ln = lane & 15;
    const int qd = lane >> 4;
    const int wm = (wave & 1) * 64;
    const int wn = ((wave >> 1) & 1) * 64;

    for (int mt = 0; mt < 16; mt++) {
      const int m0 = bb * 2048 + mt * 128;
      for (int nh = 0; nh < 2; nh++) {
        const int n0 = pp * 256 + nh * 128;
        f32x4 acc[4][4] = {};
        for (int kc = 0; kc < 10; kc++) {
          const int k0 = kc * 32;
          if (k0 < 64) {
#pragma unroll
            for (int i = 0; i < 4; i++) {
              int idx = tid + i * 256;
              int r = idx >> 3;
              int c4 = (idx & 7) * 4;
              float4 v = *(const float4*)(x + (size_t)(m0 + r) * C_ + k0 + c4);
              h2 lo, hi;
              lo.x = (_Float16)v.x; lo.y = (_Float16)v.y;
              hi.x = (_Float16)v.z; hi.y = (_Float16)v.w;
              h2* d = (h2*)&Ah[r * AKP + c4];
              d[0] = lo; d[1] = hi;
            }
          } else {
#pragma unroll
            for (int i = 0; i < 4; i++) {
              int idx = tid + i * 256;
              int r = idx >> 3;
              int c4 = (idx & 7) * 4;
              uchar4 u = *(const uchar4*)(spk + (size_t)(m0 + r) * H_ + (k0 - 64) + c4);
              h2 lo, hi;
              lo.x = (_Float16)(int)u.x; lo.y = (_Float16)(int)u.y;
              hi.x = (_Float16)(int)u.z; hi.y = (_Float16)(int)u.w;
              h2* d = (h2*)&Ah[r * AKP + c4];
              d[0] = lo; d[1] = hi;
            }
          }
#pragma unroll
          for (int i = 0; i < 4; i++) {
            int idx = tid + i * 256;
            int r = idx >> 3;
            int c4 = (idx & 7) * 4;
            float4 v = *(const float4*)(wih + (size_t)(n0 + r) * 320 + k0 + c4);
            h2 lo, hi;
            lo.x = (_Float16)v.x; lo.y = (_Float16)v.y;
            hi.x = (_Float16)v.z; hi.y = (_Float16)v.w;
            h2* d = (h2*)&Bh[r * AKP + c4];
            d[0] = lo; d[1] = hi;
          }
          __syncthreads();
          {
            f16x8 a[4], bbf[4];
#pragma unroll
            for (int mtl = 0; mtl < 4; mtl++)
              a[mtl] = *(const f16x8*)&Ah[(wm + mtl * 16 + ln) * AKP + qd * 8];
#pragma unroll
            for (int nt = 0; nt < 4; nt++)
              bbf[nt] = *(const f16x8*)&Bh[(wn + nt * 16 + ln) * AKP + qd * 8];
#pragma unroll
            for (int mtl = 0; mtl < 4; mtl++)
#pragma unroll
              for (int nt = 0; nt < 4; nt++)
                acc[mtl][nt] = __builtin_amdgcn_mfma_f32_16x16x32_f16(
                    a[mtl], bbf[nt], acc[mtl][nt], 0, 0, 0);
          }
          __syncthreads();
        }
        {
          float bias[4];
#pragma unroll
          for (int nt = 0; nt < 4; nt++) bias[nt] = bih[n0 + wn + nt * 16 + ln];
#pragma unroll
          for (int mtl = 0; mtl < 4; mtl++)
#pragma unroll
            for (int nt = 0; nt < 4; nt++) {
              int n = wn + nt * 16 + ln;
#pragma unroll
              for (int r = 0; r < 4; r++) {
                int m = wm + mtl * 16 + qd * 4 + r;
                Ct[m * CTP + n] = (_Float16)(acc[mtl][nt][r] + bias[nt]);
              }
            }
        }
        __syncthreads();
#pragma unroll
        for (int i = 0; i < 8; i++) {
          int idx = tid + i * 256;
          int r = idx >> 4;
          int c = (idx & 15) * 8;
          *(h8*)(gx + (size_t)(m0 + r) * G3_ + n0 + c) = *(const h8*)&Ct[r * CTP + c];
        }
        __syncthreads();  // stores drained before flag / Ct reuse
      }
      if (tid == 0)
        __hip_atomic_fetch_add(&flags[bb * 16 + mt], 1, __ATOMIC_RELEASE,
                               __HIP_MEMORY_SCOPE_AGENT);
    }
    return;
  }

  // ========== CONSUMER: 16 batches, MFMA (acc in AGPR), W plain VGPR ==========
  const int b0 = blockIdx.x << 4;   // batches b0..b0+15
  const int w = tid >> 6;           // wave 0..3: owns j-range [w*64, w*64+64)
  const int lb = lane & 15;         // A-row idx / B-col = batch b0+lb
  const int lk = lane >> 4;         // k-group / D-row-group

  // ---- W fragments: plain VGPR array (round-1-proven residency pattern) ----
  i32x4 wf[3][4][4];   // 192 dwords
  {
    const float qs = 2032.0f;  // 127 / 0.0625
#pragma unroll
    for (int g = 0; g < 3; g++)
#pragma unroll
      for (int jl = 0; jl < 4; jl++) {
        const float* row = whh + (size_t)(g * 256 + (w * 4 + jl) * 16 + lb) * H_;
#pragma unroll
        for (int c = 0; c < 4; c++) {
          const int kb = c * 64 + lk * 16;
          i32x4 v;
#pragma unroll
          for (int d = 0; d < 4; d++) {
            float4 f = *(const float4*)(row + kb + d * 4);
            v[d] = ((int)rintf(f.x * qs) & 255) | (((int)rintf(f.y * qs) & 255) << 8) |
                   (((int)rintf(f.z * qs) & 255) << 16) | (((int)rintf(f.w * qs) & 255) << 24);
          }
          wf[g][jl][c] = v;
        }
      }
  }

  // biases to LDS (f32), h-queue zeroed
  for (int i = tid; i < G3_; i += 256) blds[i] = bhh[i];
  for (int i = tid; i < (int)(2 * 16 * HQP / 4); i += 256) ((int*)hlds)[i] = 0;
  float ho[16];
#pragma unroll
  for (int i = 0; i < 16; i++) ho[i] = 0.f;
  __syncthreads();

  // per-lane gx base: batch b0+lb, this wave's j-offset, k-group lk
  const _Float16* gxT = gx + (size_t)(b0 + lb) * T_ * G3_ + w * 64 + lk * 4;
  int p = 0;
  for (int mt = 0; mt < 16; mt++) {
    if (tid < 16) {
      while (__hip_atomic_load(&flags[(b0 + tid) * 16 + mt], __ATOMIC_ACQUIRE,
                               __HIP_MEMORY_SCOPE_AGENT) < 3)
        __builtin_amdgcn_s_sleep(8);
    }
    __syncthreads();

    for (int tt = 0; tt < 128; tt++) {
      // gx for this step's 16 (j,b) pairs: 12 x b64, issued first
      const _Float16* gp = gxT + (size_t)(mt * 128 + tt) * G3_;
      h4v gv[3][4];
#pragma unroll
      for (int g = 0; g < 3; g++)
#pragma unroll
        for (int jl = 0; jl < 4; jl++)
          gv[g][jl] = *(const h4v*)(gp + g * 256 + jl * 16);

      // h B-fragments: row b (= lb), k-contiguous
      i32x4 hf[4];
#pragma unroll
      for (int c = 0; c < 4; c++)
        hf[c] = *(const i32x4*)&hlds[p][lb][c * 64 + lk * 16];

      // 48 MFMA: A,B from VGPR, C/D accumulates in AGPR ("+a" — the only
      // operand the RA reliably AGPR-homes). i32 exact == sdot4 path.
      i32x4 acc[3][4];
#pragma unroll
      for (int g = 0; g < 3; g++)
#pragma unroll
        for (int jl = 0; jl < 4; jl++) {
          i32x4 a = {0, 0, 0, 0};
          asm volatile(
              "s_nop 1\n\t"  // accvgpr_write(zero-init) -> MFMA C-read hazard
              "v_mfma_i32_16x16x64_i8 %0, %1, %5, %0\n\t"
              "v_mfma_i32_16x16x64_i8 %0, %2, %6, %0\n\t"
              "v_mfma_i32_16x16x64_i8 %0, %3, %7, %0\n\t"
              "v_mfma_i32_16x16x64_i8 %0, %4, %8, %0"
              : "+a"(a)
              : "v"(wf[g][jl][0]), "v"(wf[g][jl][1]),
                "v"(wf[g][jl][2]), "v"(wf[g][jl][3]),
                "v"(hf[0]), "v"(hf[1]), "v"(hf[2]), "v"(hf[3]));
          acc[g][jl] = a;
        }
      asm volatile("s_nop 7\n\ts_nop 7");  // MFMA write -> accvgpr_read hazard

      // tail: 16 (j, b=lb) pairs; compiler emits accvgpr_read at acc uses
#pragma unroll
      for (int jl = 0; jl < 4; jl++) {
        const int jb = (w * 4 + jl) * 16 + lk * 4;
        const float4 bR4 = *(const float4*)&blds[jb];
        const float4 bZ4 = *(const float4*)&blds[H_ + jb];
        const float4 bN4 = *(const float4*)&blds[2 * H_ + jb];
        int packed = 0;
#pragma unroll
        for (int r = 0; r < 4; r++) {
          const float xr = (float)gv[0][jl][r];
          const float xz = (float)gv[1][jl][r];
          const float xn = (float)gv[2][jl][r];
          const float bRr = (r == 0) ? bR4.x : (r == 1) ? bR4.y : (r == 2) ? bR4.z : bR4.w;
          const float bZr = (r == 0) ? bZ4.x : (r == 1) ? bZ4.y : (r == 2) ? bZ4.z : bZ4.w;
          const float bNr = (r == 0) ? bN4.x : (r == 1) ? bN4.y : (r == 2) ? bN4.z : bN4.w;
          const float ar = (float)acc[0][jl][r] * DQ_ + bRr;
          const float az = (float)acc[1][jl][r] * DQ_ + bZr;
          const float an = (float)acc[2][jl][r] * DQ_ + bNr;
          const float rr = 1.f / (1.f + __expf(-(xr + ar)));
          const float zz = 1.f / (1.f + __expf(-(xz + az)));
          const float pre = xn + rr * an;
          const float e = __expf(2.f * pre);   // tanh = 1 - 2/(e^{2x}+1)
          const float nn = 1.f - 2.f / (e + 1.f);
          const float h = (1.f - zz) * nn + zz * ho[jl * 4 + r];
          ho[jl * 4 + r] = h;
          packed |= ((int)rintf(h * 127.0f) & 255) << (8 * r);
        }
        *(int*)&hlds[p ^ 1][lb][jb] = packed;
      }
      p ^= 1;
      __syncthreads();   // the ONLY barrier per step
    }
  }

  // ---- head: h [16 x 256] -> out [16 x 96] ----
#pragma unroll
  for (int jl = 0; jl < 4; jl++)
#pragma unroll
    for (int r = 0; r < 4; r++)
      hb32[lb][w * 64 + jl * 16 + lk * 4 + r] = ho[jl * 4 + r];
  __syncthreads();

#pragma unroll
  for (int i = 0; i < 6; i++) {
    const int o = tid + i * 256;          // 0..1535
    const int bb2 = o / 96, rr2 = o % 96;
    const float4* hw = (const float4*)(head_w + (size_t)rr2 * H_);
    const float4* hv = (const float4*)&hb32[bb2][0];
    float acc2 = head_b[rr2];
#pragma unroll
    for (int q = 0; q < H_ / 4; q++) {
      float4 w4 = hw[q];
      float4 v4 = hv[q];
      acc2 += w4.x * v4.x + w4.y * v4.y + w4.z * v4.z + w4.w * v4.w;
    }
    out[(size_t)(b0 + bb2) * HOR_ + rr2] = acc2;
  }
}

// ---------------------------------------------------------------------------
extern "C" void kernel_launch(void* const* d_in, const int* in_sizes, int n_in,
                              void* d_out, int out_size, void* d_ws, size_t ws_size,
                              hipStream_t stream) {
  const float* x      = (const float*)d_in[0];
  const float* snn_w  = (const float*)d_in[1];
  const float* snn_b  = (const float*)d_in[2];
  const float* wih    = (const float*)d_in[3];
  const float* whh    = (const float*)d_in[4];
  const float* bih    = (const float*)d_in[5];
  const float* bhh    = (const float*)d_in[6];
  const float* head_w = (const float*)d_in[7];
  const float* head_b = (const float*)d_in[8];
  float* out = (float*)d_out;

  // ws layout (235 MB + 4 KB flags):
  //   [0, 201326592)          gx fp16 [131072,768]
  //   [0, 134217728)          cur fp32 [131072,256] — alias, dead before fused
  //   [201326592, 234881024)  spk u8 [131072,256]
  //   [234881024, 234885120)  flags int[1024]
  char* ws = (char*)d_ws;
  _Float16* gx = (_Float16*)ws;
  float* cur = (float*)ws;
  unsigned char* spk = (unsigned char*)(ws + (size_t)201326592);
  int* flags = (int*)(ws + (size_t)234881024);

  k_cur<<<dim3(B_, T_ / K1_TT), 256, 0, stream>>>(x, snn_w, snn_b, cur, flags);
  k_lif<<<dim3(256), 64, 0, stream>>>(cur, spk);
  k_fused<<<dim3(196), 256, 0, stream>>>(x, spk, wih, bih, gx, whh, bhh,
                                         head_w, head_b, out, flags);
}

// Round 11
// 2233.799 us; speedup vs baseline: 3.7070x; 3.0630x over previous
//
#include <hip/hip_runtime.h>
#include <cstdint>
#include <cstddef>

#define B_   64
#define T_   2048
#define C_   64
#define H_   256
#define G3_  768    // 3*H
#define HOR_ 96

typedef _Float16 h2 __attribute__((ext_vector_type(2)));
typedef _Float16 h8 __attribute__((ext_vector_type(8)));
typedef _Float16 f16x8 __attribute__((ext_vector_type(8)));
typedef float f32x4 __attribute__((ext_vector_type(4)));

// ---------------------------------------------------------------------------
// K1: cur[b,t,h] = sum_c x[b,t,c]*snn_w[h,c] + snn_b[h]   (fp32)
// Block (0,0) also zeroes the producer->consumer flags.
// ---------------------------------------------------------------------------
#define K1_TT 128
__global__ __launch_bounds__(256) void k_cur(const float* __restrict__ x,
                                             const float* __restrict__ w,
                                             const float* __restrict__ bias,
                                             float* __restrict__ cur,
                                             int* __restrict__ flags) {
  __shared__ float xs[K1_TT * C_];  // 32 KB
  const int b = blockIdx.x;
  const int t0 = blockIdx.y * K1_TT;
  const int tid = threadIdx.x;

  if (b == 0 && blockIdx.y == 0) {
#pragma unroll
    for (int i = 0; i < 4; i++) flags[tid + i * 256] = 0;
  }

  const float4* xsrc = (const float4*)(x + ((size_t)b * T_ + t0) * C_);
  float4* xdst = (float4*)xs;
#pragma unroll
  for (int i = 0; i < (K1_TT * C_ / 4) / 256; i++)
    xdst[tid + i * 256] = xsrc[tid + i * 256];

  float wr[C_];
  const float4* wp = (const float4*)(w + (size_t)tid * C_);
#pragma unroll
  for (int q = 0; q < C_ / 4; q++) {
    float4 v = wp[q];
    wr[4 * q + 0] = v.x; wr[4 * q + 1] = v.y;
    wr[4 * q + 2] = v.z; wr[4 * q + 3] = v.w;
  }
  const float bb = bias[tid];
  __syncthreads();

  for (int t = 0; t < K1_TT; t++) {
    const float4* xrow = (const float4*)(xs + t * C_);
    float a0 = 0.f, a1 = 0.f;
#pragma unroll
    for (int q = 0; q < C_ / 4; q += 2) {
      float4 v0 = xrow[q];
      float4 v1 = xrow[q + 1];
      a0 += wr[4 * q + 0] * v0.x + wr[4 * q + 1] * v0.y +
            wr[4 * q + 2] * v0.z + wr[4 * q + 3] * v0.w;
      a1 += wr[4 * q + 4] * v1.x + wr[4 * q + 5] * v1.y +
            wr[4 * q + 6] * v1.z + wr[4 * q + 7] * v1.w;
    }
    cur[((size_t)b * T_ + t0 + t) * H_ + tid] = a0 + a1 + bb;
  }
}

// ---------------------------------------------------------------------------
// K2: LIF scan per (b,h). Spikes stored as u8 (exact).
// ROUND-11: unroll 32 -> 64. Latency-bound scan: 16K threads, stride-1KB
// loads; in-flight bytes double (2->4 MB) => effective BW ~2.2->~4.4 TB/s.
// Numerics identical (same loads, same serial FMA order, deeper pipeline).
// ---------------------------------------------------------------------------
__global__ __launch_bounds__(64) void k_lif(const float* __restrict__ cur,
                                            unsigned char* __restrict__ spk) {
  const int b = blockIdx.x >> 2;
  const int h = ((blockIdx.x & 3) << 6) + threadIdx.x;
  const float* cp = cur + (size_t)b * T_ * H_ + h;
  unsigned char* sp = spk + (size_t)b * T_ * H_ + h;
  float mem = 0.f;
#pragma unroll 64
  for (int t = 0; t < T_; t++) {
    float c = cp[(size_t)t * H_];
    float reset = (mem > 1.0f) ? 1.0f : 0.0f;  // from previous mem
    mem = 0.9f * mem + c - reset;              // THR = 1
    sp[(size_t)t * H_] = (mem > 1.0f) ? (unsigned char)1 : (unsigned char)0;
  }
}

// ---------------------------------------------------------------------------
// K3+K4 FUSED — 256 threads/block (round-1 structure, 1630-1640us verified
// in rounds 1/4/5). ROUND-11: FINAL REVERT. The MFMA consumer (rounds 6-10)
// is toolchain-dead: 4 register-allocation strategies (512thr/128-budget,
// 256thr unified-file, asm "a" inputs, asm "+a" acc) all spilled W or
// round-tripped it through scratch (6.5-8ms, FETCH ~W-footprint/step).
// Numerics were correct every time (absmax canary) — the allocator never
// cooperated. Consumer ladder summary:
//   r2 +waves/shfl-split: NEGATIVE (barrier-locked scan, issue invariant)
//   r3 2-batch: SPILL (VGPR cliff)   r4 LDS skew pipeline: NULL
//   r5 gx-load pin: NULL (not load-latency-bound)
// This file = round-5 verified source verbatim (k_fused untouched).
//  blocks 0..63   : GRU consumer, batch b.
//  blocks 64..255 : gx producers — 3 per batch (round-11 MFMA tile).
// Handoff: flags[b*16+mt] RELEASE/AGENT add, ACQUIRE spin per 128-step
// chunk. 256 blocks <= 256 CUs -> co-resident, deadlock-free.
// ---------------------------------------------------------------------------
#define GM 128
#define GN 128
#define AKP 40   // padded K-chunk stride (halves)
#define CTP 136  // C-transpose row stride (halves)
#define DQ_ (0.0625f / (127.0f * 127.0f))
__global__ __launch_bounds__(256) void k_fused(
    const float* __restrict__ x, const unsigned char* __restrict__ spk,
    const float* __restrict__ wih, const float* __restrict__ bih,
    _Float16* __restrict__ gx, const float* __restrict__ whh,
    const float* __restrict__ bhh, const float* __restrict__ head_w,
    const float* __restrict__ head_b, float* __restrict__ out,
    int* __restrict__ flags) {
  alignas(16) __shared__ _Float16 Ah[GM * AKP];  // 10 KB (producer)
  alignas(16) __shared__ _Float16 Bh[GN * AKP];  // 10 KB (producer)
  alignas(16) __shared__ _Float16 Ct[GM * CTP];  // 34 KB (producer)
  alignas(16) __shared__ int hq[2][64];          // 512 B (consumer)
  __shared__ float hbuf32[H_];                   // 1 KB (consumer)

  const int tid = threadIdx.x;
  const int lane = tid & 63;

  if (blockIdx.x >= 64) {
    // ===================== PRODUCER (round-11 tile, 256 thr) =====================
    const int pidx = blockIdx.x - 64;
    const int bb = pidx / 3;
    const int pp = pidx - bb * 3;
    const int wave = tid >> 6;        // 0..3
    const int ln = lane & 15;
    const int qd = lane >> 4;
    const int wm = (wave & 1) * 64;
    const int wn = ((wave >> 1) & 1) * 64;

    for (int mt = 0; mt < 16; mt++) {
      const int m0 = bb * 2048 + mt * 128;
      for (int nh = 0; nh < 2; nh++) {
        const int n0 = pp * 256 + nh * 128;
        f32x4 acc[4][4] = {};
        for (int kc = 0; kc < 10; kc++) {
          const int k0 = kc * 32;
          if (k0 < 64) {
#pragma unroll
            for (int i = 0; i < 4; i++) {
              int idx = tid + i * 256;
              int r = idx >> 3;
              int c4 = (idx & 7) * 4;
              float4 v = *(const float4*)(x + (size_t)(m0 + r) * C_ + k0 + c4);
              h2 lo, hi;
              lo.x = (_Float16)v.x; lo.y = (_Float16)v.y;
              hi.x = (_Float16)v.z; hi.y = (_Float16)v.w;
              h2* d = (h2*)&Ah[r * AKP + c4];
              d[0] = lo; d[1] = hi;
            }
          } else {
#pragma unroll
            for (int i = 0; i < 4; i++) {
              int idx = tid + i * 256;
              int r = idx >> 3;
              int c4 = (idx & 7) * 4;
              uchar4 u = *(const uchar4*)(spk + (size_t)(m0 + r) * H_ + (k0 - 64) + c4);
              h2 lo, hi;
              lo.x = (_Float16)(int)u.x; lo.y = (_Float16)(int)u.y;
              hi.x = (_Float16)(int)u.z; hi.y = (_Float16)(int)u.w;
              h2* d = (h2*)&Ah[r * AKP + c4];
              d[0] = lo; d[1] = hi;
            }
          }
#pragma unroll
          for (int i = 0; i < 4; i++) {
            int idx = tid + i * 256;
            int r = idx >> 3;
            int c4 = (idx & 7) * 4;
            float4 v = *(const float4*)(wih + (size_t)(n0 + r) * 320 + k0 + c4);
            h2 lo, hi;
            lo.x = (_Float16)v.x; lo.y = (_Float16)v.y;
            hi.x = (_Float16)v.z; hi.y = (_Float16)v.w;
            h2* d = (h2*)&Bh[r * AKP + c4];
            d[0] = lo; d[1] = hi;
          }
          __syncthreads();
          {
            f16x8 a[4], bbf[4];
#pragma unroll
            for (int mtl = 0; mtl < 4; mtl++)
              a[mtl] = *(const f16x8*)&Ah[(wm + mtl * 16 + ln) * AKP + qd * 8];
#pragma unroll
            for (int nt = 0; nt < 4; nt++)
              bbf[nt] = *(const f16x8*)&Bh[(wn + nt * 16 + ln) * AKP + qd * 8];
#pragma unroll
            for (int mtl = 0; mtl < 4; mtl++)
#pragma unroll
              for (int nt = 0; nt < 4; nt++)
                acc[mtl][nt] = __builtin_amdgcn_mfma_f32_16x16x32_f16(
                    a[mtl], bbf[nt], acc[mtl][nt], 0, 0, 0);
          }
          __syncthreads();
        }
        {
          float bias[4];
#pragma unroll
          for (int nt = 0; nt < 4; nt++) bias[nt] = bih[n0 + wn + nt * 16 + ln];
#pragma unroll
          for (int mtl = 0; mtl < 4; mtl++)
#pragma unroll
            for (int nt = 0; nt < 4; nt++) {
              int n = wn + nt * 16 + ln;
#pragma unroll
              for (int r = 0; r < 4; r++) {
                int m = wm + mtl * 16 + qd * 4 + r;
                Ct[m * CTP + n] = (_Float16)(acc[mtl][nt][r] + bias[nt]);
              }
            }
        }
        __syncthreads();
#pragma unroll
        for (int i = 0; i < 8; i++) {
          int idx = tid + i * 256;
          int r = idx >> 4;
          int c = (idx & 15) * 8;
          *(h8*)(gx + (size_t)(m0 + r) * G3_ + n0 + c) = *(const h8*)&Ct[r * CTP + c];
        }
        __syncthreads();  // stores drained before flag / Ct reuse
      }
      if (tid == 0)
        __hip_atomic_fetch_add(&flags[bb * 16 + mt], 1, __ATOMIC_RELEASE,
                               __HIP_MEMORY_SCOPE_AGENT);
    }
    return;
  }

  // ========== CONSUMER: 3 rows/thread, full K, pinned-early gx prefetch ==========
  const int b = blockIdx.x;
  const int j = tid;   // 0..255: owns whh rows {j, j+256, j+512}, full K

  // quantize 3 full rows -> 192 packed i8x4 dwords (arch VGPRs @ 256 budget)
  int wr[64], wz[64], wn2[64];
  {
    const float qs = 2032.0f;  // 127 / 0.0625
    const float4* p0 = (const float4*)(whh + (size_t)j * H_);
    const float4* p1 = (const float4*)(whh + (size_t)(H_ + j) * H_);
    const float4* p2 = (const float4*)(whh + (size_t)(2 * H_ + j) * H_);
#pragma unroll
    for (int q = 0; q < 64; q++) {
      float4 a = p0[q];
      wr[q] = ((int)rintf(a.x * qs) & 255) | (((int)rintf(a.y * qs) & 255) << 8) |
              (((int)rintf(a.z * qs) & 255) << 16) | (((int)rintf(a.w * qs) & 255) << 24);
      float4 c = p1[q];
      wz[q] = ((int)rintf(c.x * qs) & 255) | (((int)rintf(c.y * qs) & 255) << 8) |
              (((int)rintf(c.z * qs) & 255) << 16) | (((int)rintf(c.w * qs) & 255) << 24);
      float4 d = p2[q];
      wn2[q] = ((int)rintf(d.x * qs) & 255) | (((int)rintf(d.y * qs) & 255) << 8) |
               (((int)rintf(d.z * qs) & 255) << 16) | (((int)rintf(d.w * qs) & 255) << 24);
    }
  }
  const float br_ = bhh[j], bz_ = bhh[H_ + j], bn_ = bhh[2 * H_ + j];

  if (tid < 128) ((int*)hq)[tid] = 0;
  float hj = 0.f;
  __syncthreads();

  const _Float16* gxb = gx + (size_t)b * T_ * G3_;
  int p = 0;
  for (int mt = 0; mt < 16; mt++) {
    if (tid == 0) {
      while (__hip_atomic_load(&flags[b * 16 + mt], __ATOMIC_ACQUIRE,
                               __HIP_MEMORY_SCOPE_AGENT) < 3)
        __builtin_amdgcn_s_sleep(8);
    }
    __syncthreads();

    const _Float16* gc = gxb + (size_t)mt * 128 * G3_;
    _Float16 pr = gc[j], pz = gc[H_ + j], pn = gc[2 * H_ + j];

    for (int tt = 0; tt < 128; tt++) {
      // ---- pinned-early prefetch for step tt+1: issue FIRST, so the whole
      // sdot block covers the L3 latency before the barrier's vmcnt(0) drain.
      _Float16 npr = pr, npz = pz, npn = pn;
      if (tt < 127) {
        const _Float16* g = gc + (size_t)(tt + 1) * G3_;
        npr = g[j]; npz = g[H_ + j]; npn = g[2 * H_ + j];
      }
      __builtin_amdgcn_sched_barrier(0);  // nothing crosses: loads stay HERE

      float xr = (float)pr, xz = (float)pz, xn = (float)pn;

      // 192 sdot4 over full K, skew-1 read pipeline (round-4, neutral but
      // harmless). Integer adds reassociate exactly -> bit-identical.
      const int4* hb4 = (const int4*)hq[p];
      int ar0 = 0, ar1 = 0, az0 = 0, az1 = 0, an0 = 0, an1 = 0;
      int4 c0 = hb4[0], c1 = hb4[1], c2 = hb4[2], c3 = hb4[3];
#pragma unroll
      for (int g = 0; g < 4; g++) {
        int4 n0, n1, n2, n3;
        if (g < 3) {
          n0 = hb4[g * 4 + 4]; n1 = hb4[g * 4 + 5];
          n2 = hb4[g * 4 + 6]; n3 = hb4[g * 4 + 7];
        }
#pragma unroll
        for (int cc = 0; cc < 4; cc++) {
          int4 hv = (cc == 0) ? c0 : (cc == 1) ? c1 : (cc == 2) ? c2 : c3;
#pragma unroll
          for (int i = 0; i < 4; i++) {
            int h4 = (i == 0) ? hv.x : (i == 1) ? hv.y : (i == 2) ? hv.z : hv.w;
            int wi = g * 16 + cc * 4 + i;      // 0..63
            if (wi & 1) {
              ar1 = __builtin_amdgcn_sdot4(wr[wi], h4, ar1, false);
              az1 = __builtin_amdgcn_sdot4(wz[wi], h4, az1, false);
              an1 = __builtin_amdgcn_sdot4(wn2[wi], h4, an1, false);
            } else {
              ar0 = __builtin_amdgcn_sdot4(wr[wi], h4, ar0, false);
              az0 = __builtin_amdgcn_sdot4(wz[wi], h4, az0, false);
              an0 = __builtin_amdgcn_sdot4(wn2[wi], h4, an0, false);
            }
          }
        }
        __builtin_amdgcn_sched_barrier(2 | 4 | 16 | 32 | 64);  // DS bounded
        if (g < 3) { c0 = n0; c1 = n1; c2 = n2; c3 = n3; }
      }
      int ar = ar0 + ar1, az = az0 + az1, an = an0 + an1;

      // gates fully in-register (thread j owns r/z/n of the same j)
      float r = 1.f / (1.f + __expf(-(xr + (float)ar * DQ_ + br_)));
      float z = 1.f / (1.f + __expf(-(xz + (float)az * DQ_ + bz_)));
      float pre = xn + r * ((float)an * DQ_ + bn_);
      float e = __expf(2.f * pre);          // tanh(x) = 1 - 2/(e^{2x}+1)
      float n = 1.f - 2.f / (e + 1.f);
      hj = (1.f - z) * n + z * hj;

      ((char*)hq[p ^ 1])[j] = (char)(int)rintf(hj * 127.0f);
      pr = npr; pz = npz; pn = npn;
      p ^= 1;
      __syncthreads();   // the ONLY barrier per step
    }
  }

  hbuf32[j] = hj;
  __syncthreads();

  if (tid < HOR_) {
    const float4* hw = (const float4*)(head_w + (size_t)tid * H_);
    const float4* hv4 = (const float4*)hbuf32;
    float acc = head_b[tid];
#pragma unroll
    for (int q = 0; q < H_ / 4; q++) {
      float4 w4 = hw[q];
      float4 v4 = hv4[q];
      acc += w4.x * v4.x + w4.y * v4.y + w4.z * v4.z + w4.w * v4.w;
    }
    out[(size_t)b * HOR_ + tid] = acc;
  }
}

// ---------------------------------------------------------------------------
extern "C" void kernel_launch(void* const* d_in, const int* in_sizes, int n_in,
                              void* d_out, int out_size, void* d_ws, size_t ws_size,
                              hipStream_t stream) {
  const float* x      = (const float*)d_in[0];
  const float* snn_w  = (const float*)d_in[1];
  const float* snn_b  = (const float*)d_in[2];
  const float* wih    = (const float*)d_in[3];
  const float* whh    = (const float*)d_in[4];
  const float* bih    = (const float*)d_in[5];
  const float* bhh    = (const float*)d_in[6];
  const float* head_w = (const float*)d_in[7];
  const float* head_b = (const float*)d_in[8];
  float* out = (float*)d_out;

  // ws layout (235 MB + 4 KB flags):
  //   [0, 201326592)          gx fp16 [131072,768]
  //   [0, 134217728)          cur fp32 [131072,256] — alias, dead before fused
  //   [201326592, 234881024)  spk u8 [131072,256]
  //   [234881024, 234885120)  flags int[1024]
  char* ws = (char*)d_ws;
  _Float16* gx = (_Float16*)ws;
  float* cur = (float*)ws;
  unsigned char* spk = (unsigned char*)(ws + (size_t)201326592);
  int* flags = (int*)(ws + (size_t)234881024);

  k_cur<<<dim3(B_, T_ / K1_TT), 256, 0, stream>>>(x, snn_w, snn_b, cur, flags);
  k_lif<<<dim3(256), 64, 0, stream>>>(cur, spk);
  k_fused<<<dim3(256), 256, 0, stream>>>(x, spk, wih, bih, gx, whh, bhh,
                                         head_w, head_b, out, flags);
}

// Round 12
// 1973.264 us; speedup vs baseline: 4.1964x; 1.1320x over previous
//
#include <hip/hip_runtime.h>
#include <cstdint>
#include <cstddef>

#define B_   64
#define T_   2048
#define C_   64
#define H_   256
#define G3_  768    // 3*H
#define HOR_ 96

typedef _Float16 h2 __attribute__((ext_vector_type(2)));
typedef _Float16 h8 __attribute__((ext_vector_type(8)));
typedef _Float16 f16x8 __attribute__((ext_vector_type(8)));
typedef float f32x4 __attribute__((ext_vector_type(4)));

// ---------------------------------------------------------------------------
// k_zero: zero the 1024 combined flags (replaces k_cur's flag-zeroing).
// ---------------------------------------------------------------------------
__global__ __launch_bounds__(256) void k_zero(int* __restrict__ flags) {
#pragma unroll
  for (int i = 0; i < 4; i++) flags[threadIdx.x + i * 256] = 0;
}

// ---------------------------------------------------------------------------
// K-FUSED (single compute kernel) — 256 threads/block, 256 blocks.
// ROUND-12: eliminate the serial prefix. k_cur+k_lif (~200-220us of the 1848
// total, incl. launch gaps) ran BEFORE the scan while k_fused's producers
// idle ~95% of each 101us consumer chunk. Now producer 0 of each batch team
// computes cur+LIF CHUNK-WISE (128 t-steps, ~8us) in the consumer's shadow:
//   - x chunk staged to LDS (overlays dead Ct region)
//   - snn_w row (64 f32) in registers, EXACT k_cur accumulation expression
//   - LIF mem carried in-register across chunks => bit-identical spikes
//   - spk chunk stored to global; flag +1 (RELEASE/AGENT)
// Producers 1,2 (and 0, trivially) ACQUIRE (flag&7)>=1 before A-staging.
// gx completion adds +8 per producer; consumer waits >= 25 (1+3*8).
// cur never touches HBM (removes 268 MB traffic). Consumer: round-5 source
// VERBATIM (1620-1649us verified in rounds 1/4/5/11).
// Prior-session round-17 lesson: whole-batch cur+LIF as a serial prefix on
// one block regressed (1628->2000); chunk-wise pipelining is the fix.
// MFMA consumer branch (rounds 6-10): toolchain-dead, 4 regalloc strategies
// all spilled W; numerics were correct each time (absmax canary).
//  blocks 0..63   : GRU consumer, batch b.
//  blocks 64..255 : producers — 3 per batch; pp=0 also owns cur+LIF chunks.
// 256 blocks <= 256 CUs -> co-resident; producer 0 waits on nothing ->
// acyclic flag graph -> deadlock-free.
// ---------------------------------------------------------------------------
#define GM 128
#define GN 128
#define AKP 40   // padded K-chunk stride (halves)
#define CTP 136  // C-transpose row stride (halves)
#define DQ_ (0.0625f / (127.0f * 127.0f))
__global__ __launch_bounds__(256) void k_fused(
    const float* __restrict__ x, const float* __restrict__ snn_w,
    const float* __restrict__ snn_b, unsigned char* __restrict__ spk,
    const float* __restrict__ wih, const float* __restrict__ bih,
    _Float16* __restrict__ gx, const float* __restrict__ whh,
    const float* __restrict__ bhh, const float* __restrict__ head_w,
    const float* __restrict__ head_b, float* __restrict__ out,
    int* __restrict__ flags) {
  alignas(16) __shared__ _Float16 Ah[GM * AKP];  // 10 KB (producer)
  alignas(16) __shared__ _Float16 Bh[GN * AKP];  // 10 KB (producer)
  alignas(16) __shared__ _Float16 Ct[GM * CTP];  // 34 KB (producer; xs overlay)
  alignas(16) __shared__ int hq[2][64];          // 512 B (consumer)
  __shared__ float hbuf32[H_];                   // 1 KB (consumer)

  const int tid = threadIdx.x;
  const int lane = tid & 63;

  if (blockIdx.x >= 64) {
    // ===================== PRODUCER (round-1 tile, 256 thr) =====================
    const int pidx = blockIdx.x - 64;
    const int bb = pidx / 3;
    const int pp = pidx - bb * 3;
    const int wave = tid >> 6;        // 0..3
    const int ln = lane & 15;
    const int qd = lane >> 4;
    const int wm = (wave & 1) * 64;
    const int wn = ((wave >> 1) & 1) * 64;

    // pp==0 persistent state: snn_w row (h = tid), bias, LIF membrane.
    float wsn[C_];
    float bsn = 0.f, memv = 0.f;
    if (pp == 0) {
      const float4* wp = (const float4*)(snn_w + (size_t)tid * C_);
#pragma unroll
      for (int q = 0; q < C_ / 4; q++) {
        float4 v = wp[q];
        wsn[4 * q + 0] = v.x; wsn[4 * q + 1] = v.y;
        wsn[4 * q + 2] = v.z; wsn[4 * q + 3] = v.w;
      }
      bsn = snn_b[tid];
    }

    for (int mt = 0; mt < 16; mt++) {
      const int m0 = bb * 2048 + mt * 128;

      if (pp == 0) {
        // ---- cur + LIF for chunk mt (exact k_cur/k_lif numerics) ----
        float* xs = (float*)Ct;  // 32 KB overlay on dead Ct
        const float4* xsrc = (const float4*)(x + ((size_t)bb * T_ + mt * 128) * C_);
        float4* xdst = (float4*)xs;
#pragma unroll
        for (int i = 0; i < 8; i++) xdst[tid + i * 256] = xsrc[tid + i * 256];
        __syncthreads();
        unsigned char* sp = spk + ((size_t)bb * T_ + mt * 128) * H_ + tid;
        for (int t = 0; t < 128; t++) {
          const float4* xrow = (const float4*)(xs + t * C_);
          float a0 = 0.f, a1 = 0.f;
#pragma unroll
          for (int q = 0; q < C_ / 4; q += 2) {
            float4 v0 = xrow[q];
            float4 v1 = xrow[q + 1];
            a0 += wsn[4 * q + 0] * v0.x + wsn[4 * q + 1] * v0.y +
                  wsn[4 * q + 2] * v0.z + wsn[4 * q + 3] * v0.w;
            a1 += wsn[4 * q + 4] * v1.x + wsn[4 * q + 5] * v1.y +
                  wsn[4 * q + 6] * v1.z + wsn[4 * q + 7] * v1.w;
          }
          float c = a0 + a1 + bsn;
          float reset = (memv > 1.0f) ? 1.0f : 0.0f;  // from previous mem
          memv = 0.9f * memv + c - reset;             // THR = 1
          sp[(size_t)t * H_] = (memv > 1.0f) ? (unsigned char)1 : (unsigned char)0;
        }
        __syncthreads();  // drains each thread's spk stores; xs dead after
        if (tid == 0)
          __hip_atomic_fetch_add(&flags[bb * 16 + mt], 1, __ATOMIC_RELEASE,
                                 __HIP_MEMORY_SCOPE_AGENT);
      }

      // ---- all producers: spk chunk ready? (low 3 bits = spk signal) ----
      if (tid == 0) {
        while ((__hip_atomic_load(&flags[bb * 16 + mt], __ATOMIC_ACQUIRE,
                                  __HIP_MEMORY_SCOPE_AGENT) & 7) < 1)
          __builtin_amdgcn_s_sleep(8);
      }
      __syncthreads();

      for (int nh = 0; nh < 2; nh++) {
        const int n0 = pp * 256 + nh * 128;
        f32x4 acc[4][4] = {};
        for (int kc = 0; kc < 10; kc++) {
          const int k0 = kc * 32;
          if (k0 < 64) {
#pragma unroll
            for (int i = 0; i < 4; i++) {
              int idx = tid + i * 256;
              int r = idx >> 3;
              int c4 = (idx & 7) * 4;
              float4 v = *(const float4*)(x + (size_t)(m0 + r) * C_ + k0 + c4);
              h2 lo, hi;
              lo.x = (_Float16)v.x; lo.y = (_Float16)v.y;
              hi.x = (_Float16)v.z; hi.y = (_Float16)v.w;
              h2* d = (h2*)&Ah[r * AKP + c4];
              d[0] = lo; d[1] = hi;
            }
          } else {
#pragma unroll
            for (int i = 0; i < 4; i++) {
              int idx = tid + i * 256;
              int r = idx >> 3;
              int c4 = (idx & 7) * 4;
              uchar4 u = *(const uchar4*)(spk + (size_t)(m0 + r) * H_ + (k0 - 64) + c4);
              h2 lo, hi;
              lo.x = (_Float16)(int)u.x; lo.y = (_Float16)(int)u.y;
              hi.x = (_Float16)(int)u.z; hi.y = (_Float16)(int)u.w;
              h2* d = (h2*)&Ah[r * AKP + c4];
              d[0] = lo; d[1] = hi;
            }
          }
#pragma unroll
          for (int i = 0; i < 4; i++) {
            int idx = tid + i * 256;
            int r = idx >> 3;
            int c4 = (idx & 7) * 4;
            float4 v = *(const float4*)(wih + (size_t)(n0 + r) * 320 + k0 + c4);
            h2 lo, hi;
            lo.x = (_Float16)v.x; lo.y = (_Float16)v.y;
            hi.x = (_Float16)v.z; hi.y = (_Float16)v.w;
            h2* d = (h2*)&Bh[r * AKP + c4];
            d[0] = lo; d[1] = hi;
          }
          __syncthreads();
          {
            f16x8 a[4], bbf[4];
#pragma unroll
            for (int mtl = 0; mtl < 4; mtl++)
              a[mtl] = *(const f16x8*)&Ah[(wm + mtl * 16 + ln) * AKP + qd * 8];
#pragma unroll
            for (int nt = 0; nt < 4; nt++)
              bbf[nt] = *(const f16x8*)&Bh[(wn + nt * 16 + ln) * AKP + qd * 8];
#pragma unroll
            for (int mtl = 0; mtl < 4; mtl++)
#pragma unroll
              for (int nt = 0; nt < 4; nt++)
                acc[mtl][nt] = __builtin_amdgcn_mfma_f32_16x16x32_f16(
                    a[mtl], bbf[nt], acc[mtl][nt], 0, 0, 0);
          }
          __syncthreads();
        }
        {
          float bias[4];
#pragma unroll
          for (int nt = 0; nt < 4; nt++) bias[nt] = bih[n0 + wn + nt * 16 + ln];
#pragma unroll
          for (int mtl = 0; mtl < 4; mtl++)
#pragma unroll
            for (int nt = 0; nt < 4; nt++) {
              int n = wn + nt * 16 + ln;
#pragma unroll
              for (int r = 0; r < 4; r++) {
                int m = wm + mtl * 16 + qd * 4 + r;
                Ct[m * CTP + n] = (_Float16)(acc[mtl][nt][r] + bias[nt]);
              }
            }
        }
        __syncthreads();
#pragma unroll
        for (int i = 0; i < 8; i++) {
          int idx = tid + i * 256;
          int r = idx >> 4;
          int c = (idx & 15) * 8;
          *(h8*)(gx + (size_t)(m0 + r) * G3_ + n0 + c) = *(const h8*)&Ct[r * CTP + c];
        }
        __syncthreads();  // stores drained before flag / Ct reuse
      }
      if (tid == 0)
        __hip_atomic_fetch_add(&flags[bb * 16 + mt], 8, __ATOMIC_RELEASE,
                               __HIP_MEMORY_SCOPE_AGENT);
    }
    return;
  }

  // ========== CONSUMER: 3 rows/thread, full K (round-5 source, verbatim) ==========
  const int b = blockIdx.x;
  const int j = tid;   // 0..255: owns whh rows {j, j+256, j+512}, full K

  // quantize 3 full rows -> 192 packed i8x4 dwords (arch VGPRs @ 256 budget)
  int wr[64], wz[64], wn2[64];
  {
    const float qs = 2032.0f;  // 127 / 0.0625
    const float4* p0 = (const float4*)(whh + (size_t)j * H_);
    const float4* p1 = (const float4*)(whh + (size_t)(H_ + j) * H_);
    const float4* p2 = (const float4*)(whh + (size_t)(2 * H_ + j) * H_);
#pragma unroll
    for (int q = 0; q < 64; q++) {
      float4 a = p0[q];
      wr[q] = ((int)rintf(a.x * qs) & 255) | (((int)rintf(a.y * qs) & 255) << 8) |
              (((int)rintf(a.z * qs) & 255) << 16) | (((int)rintf(a.w * qs) & 255) << 24);
      float4 c = p1[q];
      wz[q] = ((int)rintf(c.x * qs) & 255) | (((int)rintf(c.y * qs) & 255) << 8) |
              (((int)rintf(c.z * qs) & 255) << 16) | (((int)rintf(c.w * qs) & 255) << 24);
      float4 d = p2[q];
      wn2[q] = ((int)rintf(d.x * qs) & 255) | (((int)rintf(d.y * qs) & 255) << 8) |
               (((int)rintf(d.z * qs) & 255) << 16) | (((int)rintf(d.w * qs) & 255) << 24);
    }
  }
  const float br_ = bhh[j], bz_ = bhh[H_ + j], bn_ = bhh[2 * H_ + j];

  if (tid < 128) ((int*)hq)[tid] = 0;
  float hj = 0.f;
  __syncthreads();

  const _Float16* gxb = gx + (size_t)b * T_ * G3_;
  int p = 0;
  for (int mt = 0; mt < 16; mt++) {
    if (tid == 0) {
      while (__hip_atomic_load(&flags[b * 16 + mt], __ATOMIC_ACQUIRE,
                               __HIP_MEMORY_SCOPE_AGENT) < 25)
        __builtin_amdgcn_s_sleep(8);
    }
    __syncthreads();

    const _Float16* gc = gxb + (size_t)mt * 128 * G3_;
    _Float16 pr = gc[j], pz = gc[H_ + j], pn = gc[2 * H_ + j];

    for (int tt = 0; tt < 128; tt++) {
      // ---- pinned-early prefetch for step tt+1 ----
      _Float16 npr = pr, npz = pz, npn = pn;
      if (tt < 127) {
        const _Float16* g = gc + (size_t)(tt + 1) * G3_;
        npr = g[j]; npz = g[H_ + j]; npn = g[2 * H_ + j];
      }
      __builtin_amdgcn_sched_barrier(0);  // nothing crosses: loads stay HERE

      float xr = (float)pr, xz = (float)pz, xn = (float)pn;

      // 192 sdot4 over full K, skew-1 read pipeline. Integer adds
      // reassociate exactly -> bit-identical.
      const int4* hb4 = (const int4*)hq[p];
      int ar0 = 0, ar1 = 0, az0 = 0, az1 = 0, an0 = 0, an1 = 0;
      int4 c0 = hb4[0], c1 = hb4[1], c2 = hb4[2], c3 = hb4[3];
#pragma unroll
      for (int g = 0; g < 4; g++) {
        int4 n0, n1, n2, n3;
        if (g < 3) {
          n0 = hb4[g * 4 + 4]; n1 = hb4[g * 4 + 5];
          n2 = hb4[g * 4 + 6]; n3 = hb4[g * 4 + 7];
        }
#pragma unroll
        for (int cc = 0; cc < 4; cc++) {
          int4 hv = (cc == 0) ? c0 : (cc == 1) ? c1 : (cc == 2) ? c2 : c3;
#pragma unroll
          for (int i = 0; i < 4; i++) {
            int h4 = (i == 0) ? hv.x : (i == 1) ? hv.y : (i == 2) ? hv.z : hv.w;
            int wi = g * 16 + cc * 4 + i;      // 0..63
            if (wi & 1) {
              ar1 = __builtin_amdgcn_sdot4(wr[wi], h4, ar1, false);
              az1 = __builtin_amdgcn_sdot4(wz[wi], h4, az1, false);
              an1 = __builtin_amdgcn_sdot4(wn2[wi], h4, an1, false);
            } else {
              ar0 = __builtin_amdgcn_sdot4(wr[wi], h4, ar0, false);
              az0 = __builtin_amdgcn_sdot4(wz[wi], h4, az0, false);
              an0 = __builtin_amdgcn_sdot4(wn2[wi], h4, an0, false);
            }
          }
        }
        __builtin_amdgcn_sched_barrier(2 | 4 | 16 | 32 | 64);  // DS bounded
        if (g < 3) { c0 = n0; c1 = n1; c2 = n2; c3 = n3; }
      }
      int ar = ar0 + ar1, az = az0 + az1, an = an0 + an1;

      // gates fully in-register (thread j owns r/z/n of the same j)
      float r = 1.f / (1.f + __expf(-(xr + (float)ar * DQ_ + br_)));
      float z = 1.f / (1.f + __expf(-(xz + (float)az * DQ_ + bz_)));
      float pre = xn + r * ((float)an * DQ_ + bn_);
      float e = __expf(2.f * pre);          // tanh(x) = 1 - 2/(e^{2x}+1)
      float n = 1.f - 2.f / (e + 1.f);
      hj = (1.f - z) * n + z * hj;

      ((char*)hq[p ^ 1])[j] = (char)(int)rintf(hj * 127.0f);
      pr = npr; pz = npz; pn = npn;
      p ^= 1;
      __syncthreads();   // the ONLY barrier per step
    }
  }

  hbuf32[j] = hj;
  __syncthreads();

  if (tid < HOR_) {
    const float4* hw = (const float4*)(head_w + (size_t)tid * H_);
    const float4* hv4 = (const float4*)hbuf32;
    float acc = head_b[tid];
#pragma unroll
    for (int q = 0; q < H_ / 4; q++) {
      float4 w4 = hw[q];
      float4 v4 = hv4[q];
      acc += w4.x * v4.x + w4.y * v4.y + w4.z * v4.z + w4.w * v4.w;
    }
    out[(size_t)b * HOR_ + tid] = acc;
  }
}

// ---------------------------------------------------------------------------
extern "C" void kernel_launch(void* const* d_in, const int* in_sizes, int n_in,
                              void* d_out, int out_size, void* d_ws, size_t ws_size,
                              hipStream_t stream) {
  const float* x      = (const float*)d_in[0];
  const float* snn_w  = (const float*)d_in[1];
  const float* snn_b  = (const float*)d_in[2];
  const float* wih    = (const float*)d_in[3];
  const float* whh    = (const float*)d_in[4];
  const float* bih    = (const float*)d_in[5];
  const float* bhh    = (const float*)d_in[6];
  const float* head_w = (const float*)d_in[7];
  const float* head_b = (const float*)d_in[8];
  float* out = (float*)d_out;

  // ws layout (235 MB + 4 KB flags; cur is GONE — computed in registers):
  //   [0, 201326592)          gx fp16 [131072,768]
  //   [201326592, 234881024)  spk u8 [131072,256]
  //   [234881024, 234885120)  flags int[1024]  (combined: +1 spk, +8 gx)
  char* ws = (char*)d_ws;
  _Float16* gx = (_Float16*)ws;
  unsigned char* spk = (unsigned char*)(ws + (size_t)201326592);
  int* flags = (int*)(ws + (size_t)234881024);

  k_zero<<<dim3(1), 256, 0, stream>>>(flags);
  k_fused<<<dim3(256), 256, 0, stream>>>(x, snn_w, snn_b, spk, wih, bih, gx,
                                         whh, bhh, head_w, head_b, out, flags);
}

// Round 13
// 1857.711 us; speedup vs baseline: 4.4575x; 1.0622x over previous
//
#include <hip/hip_runtime.h>
#include <cstdint>
#include <cstddef>

#define B_   64
#define T_   2048
#define C_   64
#define H_   256
#define G3_  768    // 3*H
#define HOR_ 96

typedef _Float16 h2 __attribute__((ext_vector_type(2)));
typedef _Float16 h8 __attribute__((ext_vector_type(8)));
typedef _Float16 f16x8 __attribute__((ext_vector_type(8)));
typedef float f32x4 __attribute__((ext_vector_type(4)));

// ---------------------------------------------------------------------------
// K1: cur[b,t,h] = sum_c x[b,t,c]*snn_w[h,c] + snn_b[h]   (fp32)
// Block (0,0) also zeroes the producer->consumer flags.
// ---------------------------------------------------------------------------
#define K1_TT 128
__global__ __launch_bounds__(256) void k_cur(const float* __restrict__ x,
                                             const float* __restrict__ w,
                                             const float* __restrict__ bias,
                                             float* __restrict__ cur,
                                             int* __restrict__ flags) {
  __shared__ float xs[K1_TT * C_];  // 32 KB
  const int b = blockIdx.x;
  const int t0 = blockIdx.y * K1_TT;
  const int tid = threadIdx.x;

  if (b == 0 && blockIdx.y == 0) {
#pragma unroll
    for (int i = 0; i < 4; i++) flags[tid + i * 256] = 0;
  }

  const float4* xsrc = (const float4*)(x + ((size_t)b * T_ + t0) * C_);
  float4* xdst = (float4*)xs;
#pragma unroll
  for (int i = 0; i < (K1_TT * C_ / 4) / 256; i++)
    xdst[tid + i * 256] = xsrc[tid + i * 256];

  float wr[C_];
  const float4* wp = (const float4*)(w + (size_t)tid * C_);
#pragma unroll
  for (int q = 0; q < C_ / 4; q++) {
    float4 v = wp[q];
    wr[4 * q + 0] = v.x; wr[4 * q + 1] = v.y;
    wr[4 * q + 2] = v.z; wr[4 * q + 3] = v.w;
  }
  const float bb = bias[tid];
  __syncthreads();

  for (int t = 0; t < K1_TT; t++) {
    const float4* xrow = (const float4*)(xs + t * C_);
    float a0 = 0.f, a1 = 0.f;
#pragma unroll
    for (int q = 0; q < C_ / 4; q += 2) {
      float4 v0 = xrow[q];
      float4 v1 = xrow[q + 1];
      a0 += wr[4 * q + 0] * v0.x + wr[4 * q + 1] * v0.y +
            wr[4 * q + 2] * v0.z + wr[4 * q + 3] * v0.w;
      a1 += wr[4 * q + 4] * v1.x + wr[4 * q + 5] * v1.y +
            wr[4 * q + 6] * v1.z + wr[4 * q + 7] * v1.w;
    }
    cur[((size_t)b * T_ + t0 + t) * H_ + tid] = a0 + a1 + bb;
  }
}

// ---------------------------------------------------------------------------
// K2: LIF scan per (b,h). Spikes stored as u8 (exact). unroll 32 keeps ~32
// loads in flight (round-14 fix: was latency-bound at unroll 8).
// ROUND-13 NOTE: unroll 64 (round 11) correlated with a 32ms outlier
// dispatch — dropped as null-to-harmful. Keep 32 (verified).
// ---------------------------------------------------------------------------
__global__ __launch_bounds__(64) void k_lif(const float* __restrict__ cur,
                                            unsigned char* __restrict__ spk) {
  const int b = blockIdx.x >> 2;
  const int h = ((blockIdx.x & 3) << 6) + threadIdx.x;
  const float* cp = cur + (size_t)b * T_ * H_ + h;
  unsigned char* sp = spk + (size_t)b * T_ * H_ + h;
  float mem = 0.f;
#pragma unroll 32
  for (int t = 0; t < T_; t++) {
    float c = cp[(size_t)t * H_];
    float reset = (mem > 1.0f) ? 1.0f : 0.0f;  // from previous mem
    mem = 0.9f * mem + c - reset;              // THR = 1
    sp[(size_t)t * H_] = (mem > 1.0f) ? (unsigned char)1 : (unsigned char)0;
  }
}

// ---------------------------------------------------------------------------
// K3+K4 FUSED — 256 threads/block. CHAMPION CONFIG (rounds 1/4/5: 1846.5-
// 1848.6us total, k_fused 1630-1640us, VGPR 256, no scratch).
// ROUND-13: final revert after the full search. Ladder of measured dead ends:
//   r2  512-thr pair-split:   NEGATIVE (barrier-locked scan: per-SIMD issue
//                             invariant; shfl+redundant tail added issue)
//   r3  2-batch consumer:     SPILL (VGPR 160, weights to scratch, 2633us)
//   r4  LDS skew pipeline:    NULL (h-broadcast reads not critical path)
//   r5  gx-load pinning:      NULL (not load-latency bound) — kept, harmless
//   r6-r10 MFMA consumer:     numerics correct 4x (absmax canary) but
//                             toolchain-dead: 512thr/128-budget, 256thr
//                             unified-file, asm "a" inputs, asm "+a" acc ALL
//                             spilled/round-tripped W through scratch
//   r12 full fusion:          +315us: producer ACQUIRE spins + longer
//                             producer interference window beat the ~218us
//                             serial prefix they removed
// Structural floor: ~1900cy/step = ~768cy sdot4 issue + ~200cy serial
// transcendental tail + barrier turnaround at 1 wave/SIMD, 256-VGPR cliff.
//  blocks 0..63   : GRU consumer, batch b.
//  blocks 64..255 : gx producers — 3 per batch (round-11 MFMA tile).
// Handoff: flags[b*16+mt] RELEASE/AGENT add, ACQUIRE spin per 128-step
// chunk. 256 blocks <= 256 CUs -> co-resident, deadlock-free.
// ---------------------------------------------------------------------------
#define GM 128
#define GN 128
#define AKP 40   // padded K-chunk stride (halves)
#define CTP 136  // C-transpose row stride (halves)
#define DQ_ (0.0625f / (127.0f * 127.0f))
__global__ __launch_bounds__(256) void k_fused(
    const float* __restrict__ x, const unsigned char* __restrict__ spk,
    const float* __restrict__ wih, const float* __restrict__ bih,
    _Float16* __restrict__ gx, const float* __restrict__ whh,
    const float* __restrict__ bhh, const float* __restrict__ head_w,
    const float* __restrict__ head_b, float* __restrict__ out,
    int* __restrict__ flags) {
  alignas(16) __shared__ _Float16 Ah[GM * AKP];  // 10 KB (producer)
  alignas(16) __shared__ _Float16 Bh[GN * AKP];  // 10 KB (producer)
  alignas(16) __shared__ _Float16 Ct[GM * CTP];  // 34 KB (producer)
  alignas(16) __shared__ int hq[2][64];          // 512 B (consumer)
  __shared__ float hbuf32[H_];                   // 1 KB (consumer)

  const int tid = threadIdx.x;
  const int lane = tid & 63;

  if (blockIdx.x >= 64) {
    // ===================== PRODUCER (round-11 tile, 256 thr) =====================
    const int pidx = blockIdx.x - 64;
    const int bb = pidx / 3;
    const int pp = pidx - bb * 3;
    const int wave = tid >> 6;        // 0..3
    const int ln = lane & 15;
    const int qd = lane >> 4;
    const int wm = (wave & 1) * 64;
    const int wn = ((wave >> 1) & 1) * 64;

    for (int mt = 0; mt < 16; mt++) {
      const int m0 = bb * 2048 + mt * 128;
      for (int nh = 0; nh < 2; nh++) {
        const int n0 = pp * 256 + nh * 128;
        f32x4 acc[4][4] = {};
        for (int kc = 0; kc < 10; kc++) {
          const int k0 = kc * 32;
          if (k0 < 64) {
#pragma unroll
            for (int i = 0; i < 4; i++) {
              int idx = tid + i * 256;
              int r = idx >> 3;
              int c4 = (idx & 7) * 4;
              float4 v = *(const float4*)(x + (size_t)(m0 + r) * C_ + k0 + c4);
              h2 lo, hi;
              lo.x = (_Float16)v.x; lo.y = (_Float16)v.y;
              hi.x = (_Float16)v.z; hi.y = (_Float16)v.w;
              h2* d = (h2*)&Ah[r * AKP + c4];
              d[0] = lo; d[1] = hi;
            }
          } else {
#pragma unroll
            for (int i = 0; i < 4; i++) {
              int idx = tid + i * 256;
              int r = idx >> 3;
              int c4 = (idx & 7) * 4;
              uchar4 u = *(const uchar4*)(spk + (size_t)(m0 + r) * H_ + (k0 - 64) + c4);
              h2 lo, hi;
              lo.x = (_Float16)(int)u.x; lo.y = (_Float16)(int)u.y;
              hi.x = (_Float16)(int)u.z; hi.y = (_Float16)(int)u.w;
              h2* d = (h2*)&Ah[r * AKP + c4];
              d[0] = lo; d[1] = hi;
            }
          }
#pragma unroll
          for (int i = 0; i < 4; i++) {
            int idx = tid + i * 256;
            int r = idx >> 3;
            int c4 = (idx & 7) * 4;
            float4 v = *(const float4*)(wih + (size_t)(n0 + r) * 320 + k0 + c4);
            h2 lo, hi;
            lo.x = (_Float16)v.x; lo.y = (_Float16)v.y;
            hi.x = (_Float16)v.z; hi.y = (_Float16)v.w;
            h2* d = (h2*)&Bh[r * AKP + c4];
            d[0] = lo; d[1] = hi;
          }
          __syncthreads();
          {
            f16x8 a[4], bbf[4];
#pragma unroll
            for (int mtl = 0; mtl < 4; mtl++)
              a[mtl] = *(const f16x8*)&Ah[(wm + mtl * 16 + ln) * AKP + qd * 8];
#pragma unroll
            for (int nt = 0; nt < 4; nt++)
              bbf[nt] = *(const f16x8*)&Bh[(wn + nt * 16 + ln) * AKP + qd * 8];
#pragma unroll
            for (int mtl = 0; mtl < 4; mtl++)
#pragma unroll
              for (int nt = 0; nt < 4; nt++)
                acc[mtl][nt] = __builtin_amdgcn_mfma_f32_16x16x32_f16(
                    a[mtl], bbf[nt], acc[mtl][nt], 0, 0, 0);
          }
          __syncthreads();
        }
        {
          float bias[4];
#pragma unroll
          for (int nt = 0; nt < 4; nt++) bias[nt] = bih[n0 + wn + nt * 16 + ln];
#pragma unroll
          for (int mtl = 0; mtl < 4; mtl++)
#pragma unroll
            for (int nt = 0; nt < 4; nt++) {
              int n = wn + nt * 16 + ln;
#pragma unroll
              for (int r = 0; r < 4; r++) {
                int m = wm + mtl * 16 + qd * 4 + r;
                Ct[m * CTP + n] = (_Float16)(acc[mtl][nt][r] + bias[nt]);
              }
            }
        }
        __syncthreads();
#pragma unroll
        for (int i = 0; i < 8; i++) {
          int idx = tid + i * 256;
          int r = idx >> 4;
          int c = (idx & 15) * 8;
          *(h8*)(gx + (size_t)(m0 + r) * G3_ + n0 + c) = *(const h8*)&Ct[r * CTP + c];
        }
        __syncthreads();  // stores drained before flag / Ct reuse
      }
      if (tid == 0)
        __hip_atomic_fetch_add(&flags[bb * 16 + mt], 1, __ATOMIC_RELEASE,
                               __HIP_MEMORY_SCOPE_AGENT);
    }
    return;
  }

  // ========== CONSUMER: 3 rows/thread, full K, pinned-early gx prefetch ==========
  const int b = blockIdx.x;
  const int j = tid;   // 0..255: owns whh rows {j, j+256, j+512}, full K

  // quantize 3 full rows -> 192 packed i8x4 dwords (arch VGPRs @ 256 budget)
  int wr[64], wz[64], wn2[64];
  {
    const float qs = 2032.0f;  // 127 / 0.0625
    const float4* p0 = (const float4*)(whh + (size_t)j * H_);
    const float4* p1 = (const float4*)(whh + (size_t)(H_ + j) * H_);
    const float4* p2 = (const float4*)(whh + (size_t)(2 * H_ + j) * H_);
#pragma unroll
    for (int q = 0; q < 64; q++) {
      float4 a = p0[q];
      wr[q] = ((int)rintf(a.x * qs) & 255) | (((int)rintf(a.y * qs) & 255) << 8) |
              (((int)rintf(a.z * qs) & 255) << 16) | (((int)rintf(a.w * qs) & 255) << 24);
      float4 c = p1[q];
      wz[q] = ((int)rintf(c.x * qs) & 255) | (((int)rintf(c.y * qs) & 255) << 8) |
              (((int)rintf(c.z * qs) & 255) << 16) | (((int)rintf(c.w * qs) & 255) << 24);
      float4 d = p2[q];
      wn2[q] = ((int)rintf(d.x * qs) & 255) | (((int)rintf(d.y * qs) & 255) << 8) |
               (((int)rintf(d.z * qs) & 255) << 16) | (((int)rintf(d.w * qs) & 255) << 24);
    }
  }
  const float br_ = bhh[j], bz_ = bhh[H_ + j], bn_ = bhh[2 * H_ + j];

  if (tid < 128) ((int*)hq)[tid] = 0;
  float hj = 0.f;
  __syncthreads();

  const _Float16* gxb = gx + (size_t)b * T_ * G3_;
  int p = 0;
  for (int mt = 0; mt < 16; mt++) {
    if (tid == 0) {
      while (__hip_atomic_load(&flags[b * 16 + mt], __ATOMIC_ACQUIRE,
                               __HIP_MEMORY_SCOPE_AGENT) < 3)
        __builtin_amdgcn_s_sleep(8);
    }
    __syncthreads();

    const _Float16* gc = gxb + (size_t)mt * 128 * G3_;
    _Float16 pr = gc[j], pz = gc[H_ + j], pn = gc[2 * H_ + j];

    for (int tt = 0; tt < 128; tt++) {
      // ---- pinned-early prefetch for step tt+1: issue FIRST, so the whole
      // sdot block covers the L3 latency before the barrier's vmcnt(0) drain.
      _Float16 npr = pr, npz = pz, npn = pn;
      if (tt < 127) {
        const _Float16* g = gc + (size_t)(tt + 1) * G3_;
        npr = g[j]; npz = g[H_ + j]; npn = g[2 * H_ + j];
      }
      __builtin_amdgcn_sched_barrier(0);  // nothing crosses: loads stay HERE

      float xr = (float)pr, xz = (float)pz, xn = (float)pn;

      // 192 sdot4 over full K, skew-1 read pipeline (round-4, neutral but
      // harmless). Integer adds reassociate exactly -> bit-identical.
      const int4* hb4 = (const int4*)hq[p];
      int ar0 = 0, ar1 = 0, az0 = 0, az1 = 0, an0 = 0, an1 = 0;
      int4 c0 = hb4[0], c1 = hb4[1], c2 = hb4[2], c3 = hb4[3];
#pragma unroll
      for (int g = 0; g < 4; g++) {
        int4 n0, n1, n2, n3;
        if (g < 3) {
          n0 = hb4[g * 4 + 4]; n1 = hb4[g * 4 + 5];
          n2 = hb4[g * 4 + 6]; n3 = hb4[g * 4 + 7];
        }
#pragma unroll
        for (int cc = 0; cc < 4; cc++) {
          int4 hv = (cc == 0) ? c0 : (cc == 1) ? c1 : (cc == 2) ? c2 : c3;
#pragma unroll
          for (int i = 0; i < 4; i++) {
            int h4 = (i == 0) ? hv.x : (i == 1) ? hv.y : (i == 2) ? hv.z : hv.w;
            int wi = g * 16 + cc * 4 + i;      // 0..63
            if (wi & 1) {
              ar1 = __builtin_amdgcn_sdot4(wr[wi], h4, ar1, false);
              az1 = __builtin_amdgcn_sdot4(wz[wi], h4, az1, false);
              an1 = __builtin_amdgcn_sdot4(wn2[wi], h4, an1, false);
            } else {
              ar0 = __builtin_amdgcn_sdot4(wr[wi], h4, ar0, false);
              az0 = __builtin_amdgcn_sdot4(wz[wi], h4, az0, false);
              an0 = __builtin_amdgcn_sdot4(wn2[wi], h4, an0, false);
            }
          }
        }
        __builtin_amdgcn_sched_barrier(2 | 4 | 16 | 32 | 64);  // DS bounded
        if (g < 3) { c0 = n0; c1 = n1; c2 = n2; c3 = n3; }
      }
      int ar = ar0 + ar1, az = az0 + az1, an = an0 + an1;

      // gates fully in-register (thread j owns r/z/n of the same j)
      float r = 1.f / (1.f + __expf(-(xr + (float)ar * DQ_ + br_)));
      float z = 1.f / (1.f + __expf(-(xz + (float)az * DQ_ + bz_)));
      float pre = xn + r * ((float)an * DQ_ + bn_);
      float e = __expf(2.f * pre);          // tanh(x) = 1 - 2/(e^{2x}+1)
      float n = 1.f - 2.f / (e + 1.f);
      hj = (1.f - z) * n + z * hj;

      ((char*)hq[p ^ 1])[j] = (char)(int)rintf(hj * 127.0f);
      pr = npr; pz = npz; pn = npn;
      p ^= 1;
      __syncthreads();   // the ONLY barrier per step
    }
  }

  hbuf32[j] = hj;
  __syncthreads();

  if (tid < HOR_) {
    const float4* hw = (const float4*)(head_w + (size_t)tid * H_);
    const float4* hv4 = (const float4*)hbuf32;
    float acc = head_b[tid];
#pragma unroll
    for (int q = 0; q < H_ / 4; q++) {
      float4 w4 = hw[q];
      float4 v4 = hv4[q];
      acc += w4.x * v4.x + w4.y * v4.y + w4.z * v4.z + w4.w * v4.w;
    }
    out[(size_t)b * HOR_ + tid] = acc;
  }
}

// ---------------------------------------------------------------------------
extern "C" void kernel_launch(void* const* d_in, const int* in_sizes, int n_in,
                              void* d_out, int out_size, void* d_ws, size_t ws_size,
                              hipStream_t stream) {
  const float* x      = (const float*)d_in[0];
  const float* snn_w  = (const float*)d_in[1];
  const float* snn_b  = (const float*)d_in[2];
  const float* wih    = (const float*)d_in[3];
  const float* whh    = (const float*)d_in[4];
  const float* bih    = (const float*)d_in[5];
  const float* bhh    = (const float*)d_in[6];
  const float* head_w = (const float*)d_in[7];
  const float* head_b = (const float*)d_in[8];
  float* out = (float*)d_out;

  // ws layout (235 MB + 4 KB flags):
  //   [0, 201326592)          gx fp16 [131072,768]
  //   [0, 134217728)          cur fp32 [131072,256] — alias, dead before fused
  //   [201326592, 234881024)  spk u8 [131072,256]
  //   [234881024, 234885120)  flags int[1024]
  char* ws = (char*)d_ws;
  _Float16* gx = (_Float16*)ws;
  float* cur = (float*)ws;
  unsigned char* spk = (unsigned char*)(ws + (size_t)201326592);
  int* flags = (int*)(ws + (size_t)234881024);

  k_cur<<<dim3(B_, T_ / K1_TT), 256, 0, stream>>>(x, snn_w, snn_b, cur, flags);
  k_lif<<<dim3(256), 64, 0, stream>>>(cur, spk);
  k_fused<<<dim3(256), 256, 0, stream>>>(x, spk, wih, bih, gx, whh, bhh,
                                         head_w, head_b, out, flags);
}